// Round 11
// baseline (347.788 us; speedup 1.0000x reference)
//
#include <hip/hip_runtime.h>
#include <hip/hip_bf16.h>
#include <math.h>

// ---------------------------------------------------------------------------
// SABlock_CrossMamba. R10 = R8 resubmit (3rd infra timeout; R8 never ran).
// R8 = R7 + alias fix: YACCB aliases DBLX (dead after k_prep); R7's YACCB=F2B
// overflowed into SQ1/SQ2 -> NaN via rsqrt(neg var). Scan: packed bf16 dt/dx +
// packed B|C rows + writelane; W' fold; BN-in-GEMM; fused DFT+freq. 15 launches.
// ---------------------------------------------------------------------------

constexpr int NT = 2048;
constexpr int Di = 256;
constexpr float EPSF = 1e-5f;
constexpr float LOG2E = 1.4426950408889634f;
constexpr float ISQ512 = 0.04419417382415922f;  // 1/sqrt(512)

typedef __attribute__((ext_vector_type(8))) short short8;
typedef __attribute__((ext_vector_type(4))) float f32x4;

// ws layout (float offsets, 16B-aligned)
constexpr long O_CS2B  = 0;         // bf16 1024x512
constexpr long O_CSIB  = 262144;    // bf16 512x1024
constexpr long O_A2    = 524288;    // 16384 fl
constexpr long O_FC1B  = 540672;    // bf16 256x128
constexpr long O_FC2B  = 557056;    // bf16 128x256
constexpr long O_INPB  = 573440;    // bf16 512x128
constexpr long O_XPB2  = 606208;    // bf16 448x256 (x_proj 136 | W' 256 | pad)
constexpr long O_OPB   = 663552;    // bf16 128x256
constexpr long O_RD    = 679936;    // 256
constexpr long O_IDG   = 680192;    // 256
constexpr long O_XNB   = 680448;    // bf16 2048x128
constexpr long O_XZB   = 811520;    // bf16 2048x512
constexpr long O_XHB   = 1335808;   // bf16 4x2048x256
constexpr long O_DBLX  = 2384384;   // fp32 4x2048x392 (3211264 fl)
constexpr long O_DTDX  = 5595648;   // uint 4x256x2048 (bf16 dt|dx pair)
constexpr long O_BCT   = 7692800;   // fp32 4x2048x128 (B|C packed)
constexpr long O_YS    = 8741376;   // fp32 4x2048x256
constexpr long O_XO    = 10838528;  // fp32 2048x128
constexpr long O_LN2B  = 11100672;  // bf16 2048x128
constexpr long O_H1B   = 11231744;  // bf16 2048x256
constexpr long O_H1NTB = 11493888;  // bf16 4x256x512
constexpr long O_XRITB = 11756032;  // bf16 4x256x1024 (524288 fl)
constexpr long O_H2B   = 12280320;  // bf16 2048x256
constexpr long O_F2B   = 12542464;  // bf16 2048x128 (131072 fl)
constexpr long O_SQ1   = 12673536;  // 512
constexpr long O_SQ2   = 12674048;  // 256
// Aliases (disjoint lifetimes):
constexpr long O_XO1   = O_XRITB;   // out_proj->lndbl; XRITB written later
constexpr long O_YACCB = O_DBLX;    // yfull->out_proj; DBLX dead after k_prep
                                    // (262144 fl needed, 3211264 available)

__device__ __forceinline__ ushort bf16bits(float v) {
  __hip_bfloat16 h = __float2bfloat16(v);
  return *(ushort*)&h;
}
__device__ __forceinline__ float bfu(ushort u) {
  return __uint_as_float((uint)u << 16);
}

// ---------------------------------------------------------------------------
__global__ __launch_bounds__(256) void k_tables(
    const float* __restrict__ A_log, const float* __restrict__ fc1_w,
    const float* __restrict__ fc2_w, const float* __restrict__ r_mat,
    const float* __restrict__ i_mat, const float* __restrict__ in_proj_w,
    const float* __restrict__ x_proj_w, const float* __restrict__ dt_proj_w,
    const float* __restrict__ out_proj_w,
    const float* __restrict__ x, const float* __restrict__ ln_w,
    const float* __restrict__ ln_b, float* __restrict__ ws) {
  __shared__ float ct[512];
  int tid = threadIdx.x;
  ct[tid]       = __cosf((float)tid * (6.283185307179586f / 512.0f)) * ISQ512;
  ct[tid + 256] = __cosf((float)(tid + 256) * (6.283185307179586f / 512.0f)) * ISQ512;
  __syncthreads();
  __hip_bfloat16* cs2b = (__hip_bfloat16*)(ws + O_CS2B);
  __hip_bfloat16* csib = (__hip_bfloat16*)(ws + O_CSIB);
  int i = blockIdx.x * 256 + tid;   // 1048576 threads
  if (i < 524288) {          // CS2[r][n]: r<512 cos(rn), else -sin((r-512)n)
    int r = i >> 9, n = i & 511;
    float v;
    if (r < 512) v = ct[(r * n) & 511];
    else         v = -ct[((r - 512) * n + 384) & 511];
    cs2b[i] = __float2bfloat16(v);
  } else {                   // CSI[n][kp]: kp<512 cos(n*kp), else -sin(n(kp-512))
    int j = i - 524288;
    int n = j >> 10, kp = j & 1023;
    float v;
    if (kp < 512) v = ct[(n * kp) & 511];
    else          v = -ct[(n * (kp - 512) + 384) & 511];
    csib[j] = __float2bfloat16(v);
  }
  if (i < 16384) ws[O_A2 + i] = -expf(A_log[i]) * LOG2E;
  if (i < 32768) {
    ((__hip_bfloat16*)(ws + O_FC1B))[i] = __float2bfloat16(fc1_w[i]);
    ((__hip_bfloat16*)(ws + O_FC2B))[i] = __float2bfloat16(fc2_w[i]);
  }
  if (i < 65536) {  // INPB[n][k] = in_proj_w[k][n]  (512x128)
    int n = i >> 7, k = i & 127;
    ((__hip_bfloat16*)(ws + O_INPB))[i] = __float2bfloat16(in_proj_w[k * 512 + n]);
  }
  if (i < 114688) {  // XPB2[n][k]: n<136 x_proj^T; 136..391 W'=xp[:, :8]@dtw; pad 0
    int n = i >> 8, k = i & 255;
    float v = 0.f;
    if (n < 136) v = x_proj_w[k * 136 + n];
    else if (n < 392) {
      int d = n - 136;
#pragma unroll
      for (int r = 0; r < 8; ++r) v = fmaf(x_proj_w[k * 136 + r], dt_proj_w[r * 256 + d], v);
    }
    ((__hip_bfloat16*)(ws + O_XPB2))[i] = __float2bfloat16(v);
  }
  if (i >= 131072 && i < 163840) {  // OPB[n][k] = out_proj_w[k][n] (128x256)
    int j = i - 131072;
    int n = j >> 8, k = j & 255;
    ((__hip_bfloat16*)(ws + O_OPB))[j] = __float2bfloat16(out_proj_w[k * 128 + n]);
  }
  if (i < 256) {
    ws[O_RD + i] = r_mat[i * 256 + i];
    ws[O_IDG + i] = i_mat[i * 256 + i];
  }
  if (i < 512) ws[O_SQ1 + i] = 0.f;
  if (i < 256) ws[O_SQ2 + i] = 0.f;
  if (blockIdx.x < 512) {  // ln1, one wave per token
    ushort* outb = (ushort*)(ws + O_XNB);
    int lane = tid & 63;
    int t = (blockIdx.x * 256 + tid) >> 6;
    float v0 = x[t * 128 + lane], v1 = x[t * 128 + 64 + lane];
    float s = v0 + v1, sq = v0 * v0 + v1 * v1;
#pragma unroll
    for (int off = 32; off; off >>= 1) { s += __shfl_xor(s, off); sq += __shfl_xor(sq, off); }
    float mu = s * (1.f / 128.f);
    float rstd = rsqrtf(sq * (1.f / 128.f) - mu * mu + EPSF);
    outb[t * 128 + lane]      = bf16bits((v0 - mu) * rstd * ln_w[lane] + ln_b[lane]);
    outb[t * 128 + 64 + lane] = bf16bits((v1 - mu) * rstd * ln_w[64 + lane] + ln_b[64 + lane]);
  }
}

// ---------------------------------------------------------------------------
__global__ void k_lndbl(const float* __restrict__ x, const float* __restrict__ xo1,
                        const float* __restrict__ w1, const float* __restrict__ b1,
                        const float* __restrict__ w2, const float* __restrict__ b2,
                        float* __restrict__ xo, ushort* __restrict__ ln2b) {
  int lane = threadIdx.x & 63;
  int t = (blockIdx.x * 256 + threadIdx.x) >> 6;
  float u0 = xo1[t * 128 + lane], u1 = xo1[t * 128 + 64 + lane];
  float s = u0 + u1, sq = u0 * u0 + u1 * u1;
#pragma unroll
  for (int off = 32; off; off >>= 1) { s += __shfl_xor(s, off); sq += __shfl_xor(sq, off); }
  float mu = s * (1.f / 128.f);
  float rstd = rsqrtf(sq * (1.f / 128.f) - mu * mu + EPSF);
  float a0 = x[t * 128 + lane]      + (u0 - mu) * rstd * w1[lane] + b1[lane];
  float a1 = x[t * 128 + 64 + lane] + (u1 - mu) * rstd * w1[64 + lane] + b1[64 + lane];
  xo[t * 128 + lane] = a0;
  xo[t * 128 + 64 + lane] = a1;
  s = a0 + a1; sq = a0 * a0 + a1 * a1;
#pragma unroll
  for (int off = 32; off; off >>= 1) { s += __shfl_xor(s, off); sq += __shfl_xor(sq, off); }
  mu = s * (1.f / 128.f);
  rstd = rsqrtf(sq * (1.f / 128.f) - mu * mu + EPSF);
  ln2b[t * 128 + lane]      = bf16bits((a0 - mu) * rstd * w2[lane] + b2[lane]);
  ln2b[t * 128 + 64 + lane] = bf16bits((a1 - mu) * rstd * w2[64 + lane] + b2[64 + lane]);
}

// ---------------------------------------------------------------------------
// bf16 MFMA GEMM: C = A @ Bt^T. Epilogue guards n < N.
template <bool OUTBF16>
__global__ __launch_bounds__(256) void k_gmfma(const ushort* __restrict__ A,
                                               const ushort* __restrict__ Bt,
                                               void* __restrict__ Cv,
                                               int M, int N, int K,
                                               long sA, long sBt, long sC) {
  A += (long)blockIdx.z * sA;
  Bt += (long)blockIdx.z * sBt;
  int lane = threadIdx.x & 63, wid = threadIdx.x >> 6;
  int m0 = blockIdx.y * 64 + wid * 16, n0 = blockIdx.x * 64;
  const ushort* arow = A + (long)(m0 + (lane & 15)) * K + (lane >> 4) * 8;
  const ushort* brow = Bt + (long)(n0 + (lane & 15)) * K + (lane >> 4) * 8;
  f32x4 acc0 = {0.f, 0.f, 0.f, 0.f}, acc1 = acc0, acc2 = acc0, acc3 = acc0;
#pragma unroll 4
  for (int k0 = 0; k0 < K; k0 += 32) {
    short8 av = *(const short8*)(arow + k0);
    short8 b0 = *(const short8*)(brow + k0);
    short8 b1 = *(const short8*)(brow + 16L * K + k0);
    short8 b2 = *(const short8*)(brow + 32L * K + k0);
    short8 b3 = *(const short8*)(brow + 48L * K + k0);
    acc0 = __builtin_amdgcn_mfma_f32_16x16x32_bf16(av, b0, acc0, 0, 0, 0);
    acc1 = __builtin_amdgcn_mfma_f32_16x16x32_bf16(av, b1, acc1, 0, 0, 0);
    acc2 = __builtin_amdgcn_mfma_f32_16x16x32_bf16(av, b2, acc2, 0, 0, 0);
    acc3 = __builtin_amdgcn_mfma_f32_16x16x32_bf16(av, b3, acc3, 0, 0, 0);
  }
  int r0 = (lane >> 4) * 4, c0 = lane & 15;
#pragma unroll
  for (int j = 0; j < 4; ++j) {
    long row = m0 + r0 + j;
    float v[4] = {acc0[j], acc1[j], acc2[j], acc3[j]};
    if (OUTBF16) {
      __hip_bfloat16* C = (__hip_bfloat16*)Cv + blockIdx.z * sC;
#pragma unroll
      for (int c = 0; c < 4; ++c) {
        int n = n0 + c * 16 + c0;
        if (n < N) C[row * N + n] = __float2bfloat16(v[c]);
      }
    } else {
      float* C = (float*)Cv + blockIdx.z * sC;
#pragma unroll
      for (int c = 0; c < 4; ++c) {
        int n = n0 + c * 16 + c0;
        if (n < N) C[row * N + n] = v[c];
      }
    }
  }
}

// bf16 MFMA GEMM + per-column BN partial stats into SQ (atomics). z=1, N%64==0.
__global__ __launch_bounds__(256) void k_gmfma_bn(const ushort* __restrict__ A,
                                                  const ushort* __restrict__ Bt,
                                                  ushort* __restrict__ C,
                                                  float* __restrict__ SQ,
                                                  int N, int K) {
  int lane = threadIdx.x & 63, wid = threadIdx.x >> 6;
  int m0 = blockIdx.y * 64 + wid * 16, n0 = blockIdx.x * 64;
  const ushort* arow = A + (long)(m0 + (lane & 15)) * K + (lane >> 4) * 8;
  const ushort* brow = Bt + (long)(n0 + (lane & 15)) * K + (lane >> 4) * 8;
  f32x4 acc[4] = {{0.f, 0.f, 0.f, 0.f}, {0.f, 0.f, 0.f, 0.f},
                  {0.f, 0.f, 0.f, 0.f}, {0.f, 0.f, 0.f, 0.f}};
#pragma unroll 4
  for (int k0 = 0; k0 < K; k0 += 32) {
    short8 av = *(const short8*)(arow + k0);
#pragma unroll
    for (int c = 0; c < 4; ++c) {
      short8 bv = *(const short8*)(brow + (long)c * 16 * K + k0);
      acc[c] = __builtin_amdgcn_mfma_f32_16x16x32_bf16(av, bv, acc[c], 0, 0, 0);
    }
  }
  int r0 = (lane >> 4) * 4, c0 = lane & 15;
#pragma unroll
  for (int j = 0; j < 4; ++j) {
    long row = m0 + r0 + j;
#pragma unroll
    for (int c = 0; c < 4; ++c)
      C[row * N + n0 + c * 16 + c0] = bf16bits(acc[c][j]);
  }
#pragma unroll
  for (int c = 0; c < 4; ++c) {
    f32x4 v = acc[c];
    float s = v[0] + v[1] + v[2] + v[3];
    float q = v[0] * v[0] + v[1] * v[1] + v[2] * v[2] + v[3] * v[3];
    s += __shfl_xor(s, 16); s += __shfl_xor(s, 32);
    q += __shfl_xor(q, 16); q += __shfl_xor(q, 32);
    if ((lane >> 4) == 0) {
      int n = n0 + c * 16 + c0;
      atomicAdd(&SQ[n], s);
      atomicAdd(&SQ[N + n], q);
    }
  }
}

// ---------------------------------------------------------------------------
// Causal depthwise conv + SiLU, all 4 variants per thread (bf16 in/out).
__global__ void k_conv4(const ushort* __restrict__ xzb, const float* __restrict__ cw,
                        const float* __restrict__ cb, ushort* __restrict__ xhb) {
  int i = blockIdx.x * 256 + threadIdx.x;
  int t = i >> 8, d = i & 255;
  float w0 = cw[d * 4 + 0], w1 = cw[d * 4 + 1], w2 = cw[d * 4 + 2], w3 = cw[d * 4 + 3];
  float bias = cb[d];
  float x0  = bfu(xzb[(long)t * 512 + d]);
  float xm1 = t >= 1 ? bfu(xzb[(long)(t - 1) * 512 + d]) : 0.f;
  float xm2 = t >= 2 ? bfu(xzb[(long)(t - 2) * 512 + d]) : 0.f;
  float xm3 = t >= 3 ? bfu(xzb[(long)(t - 3) * 512 + d]) : 0.f;
  if ((t & 63) >= 3) {
    float s = fmaf(w0, xm3, fmaf(w1, xm2, fmaf(w2, xm1, fmaf(w3, x0, bias))));
    float sil = s / (1.f + expf(-s));
    ushort sb = bf16bits(sil);
#pragma unroll
    for (int v = 0; v < 4; ++v) xhb[v * 524288 + i] = sb;
  } else {
#pragma unroll
    for (int v = 0; v < 4; ++v) {
      int lv = t & ((512 >> v) - 1);
      float s = fmaf(w3, x0, bias);
      if (lv >= 1) s = fmaf(w2, xm1, s);
      if (lv >= 2) s = fmaf(w1, xm2, s);
      if (lv >= 3) s = fmaf(w0, xm3, s);
      float sil = s / (1.f + expf(-s));
      xhb[v * 524288 + i] = bf16bits(sil);
    }
  }
}

// ---------------------------------------------------------------------------
// prep: DTDX packed transpose + BCT pack + Cm copy. grid (32 t-tiles, 4 v).
__global__ __launch_bounds__(256) void k_prep(const float* __restrict__ dblx,
                                              const ushort* __restrict__ xhb,
                                              const float* __restrict__ dt_b,
                                              float* __restrict__ outC,
                                              uint* __restrict__ DTDX,
                                              float* __restrict__ BCT) {
  int v = blockIdx.y, t0 = blockIdx.x * 64;
  int tid = threadIdx.x;
  const float* dp = dblx + ((long)v * 2048 + t0) * 392;
  // BCT: cols 8..135 -> [v][t][0..127]
  float* bout = BCT + ((long)v * 2048 + t0) * 128;
#pragma unroll
  for (int it = 0; it < 32; ++it) {
    int idx = it * 256 + tid;
    int t = idx >> 7, j = idx & 127;
    bout[idx] = dp[(long)t * 392 + 8 + j];
  }
  // Cm -> out
#pragma unroll
  for (int it = 0; it < 16; ++it) {
    int idx = it * 256 + tid;
    int t = idx >> 6, s = idx & 63;
    outC[(long)v * 131072 + (long)(t0 + t) * 64 + s] = dp[(long)t * 392 + 72 + s];
  }
  // DTDX transpose in 64x64 chunks
  __shared__ uint tile[64][65];
#pragma unroll
  for (int dc = 0; dc < 4; ++dc) {
    int d0 = dc * 64;
#pragma unroll
    for (int it = 0; it < 16; ++it) {
      int idx = it * 256 + tid;
      int t = idx >> 6, dl = idx & 63;
      int d = d0 + dl;
      float logit = dp[(long)t * 392 + 136 + d] + dt_b[d];
      float dtv = fmaxf(logit, 0.f) + log1pf(expf(-fabsf(logit)));
      float xv = bfu(xhb[((long)v * 2048 + t0 + t) * 256 + d]);
      tile[t][dl] = ((uint)bf16bits(dtv * xv) << 16) | (uint)bf16bits(dtv);
    }
    __syncthreads();
#pragma unroll
    for (int it = 0; it < 16; ++it) {
      int idx = it * 256 + tid;
      int dl = idx >> 6, t = idx & 63;
      DTDX[((long)(v * 256 + d0 + dl)) * 2048 + t0 + t] = tile[t][dl];
    }
    __syncthreads();
  }
}

// ---------------------------------------------------------------------------
template <int CTRL>
__device__ __forceinline__ float dpp_add(float x) {
  int t = __builtin_amdgcn_update_dpp(0, __float_as_int(x), CTRL, 0xF, 0xF, true);
  return x + __int_as_float(t);
}

// Selective scan: packed dt/dx, packed B|C rows, writelane scatter.
__global__ __launch_bounds__(256) void k_scan(const uint* __restrict__ DTDX,
                                              const float* __restrict__ BCT,
                                              const float* __restrict__ A2,
                                              float* __restrict__ ys) {
  int lane = threadIdx.x & 63;
  int gwid = (blockIdx.x * 256 + threadIdx.x) >> 6;
  int v, base;
  if (gwid < 1024)      { v = 0; base = 0; }
  else if (gwid < 3072) { v = 1; base = 1024; }
  else if (gwid < 7168) { v = 2; base = 3072; }
  else                  { v = 3; base = 7168; }
  int local = gwid - base;
  int b = local >> 8, d = local & 255;
  int Lp = 512 >> v;
  int t0 = b * Lp;
  const uint* drow = DTDX + ((long)(v * 256 + d)) * 2048 + t0;
  const float* brow = BCT + ((long)(v * 2048 + t0)) * 128;
  float* ysp = ys + (long)v * NT * Di + (long)((b << 8) + d) * Lp;
  float a2 = A2[d * 64 + lane];
  float h = 0.f;

#define LOADG(BB, CC, G)                                                     \
  { const float* rg = rowp + (G) * 1024;                                     \
    _Pragma("unroll") for (int q = 0; q < 8; ++q) {                          \
      BB[q] = rg[q * 128 + lane];                                            \
      CC[q] = rg[q * 128 + 64 + lane];                                       \
    } }
#define PROCG(BB, CC, G)                                                     \
  _Pragma("unroll") for (int q = 0; q < 8; ++q) {                            \
    const int l2 = (G) * 8 + q;                                              \
    uint u = (uint)__builtin_amdgcn_readlane((int)rdx, l2);                  \
    float sdt = __uint_as_float(u << 16);                                    \
    float sdx = __uint_as_float(u & 0xffff0000u);                            \
    float a = __builtin_amdgcn_exp2f(sdt * a2);                              \
    h = fmaf(a, h, sdx * BB[q]);                                             \
    float p = h * CC[q];                                                     \
    p = dpp_add<0x111>(p); p = dpp_add<0x112>(p);                            \
    p = dpp_add<0x114>(p); p = dpp_add<0x118>(p);                            \
    p = dpp_add<0x142>(p); p = dpp_add<0x143>(p);                            \
    int tot = __builtin_amdgcn_readlane(__float_as_int(p), 63);              \
    asm("v_writelane_b32 %0, %1, %2" : "+v"(ybuf_i) : "s"(tot), "i"(l2));    \
  }

  for (int c = 0; c < Lp; c += 64) {
    uint rdx = drow[c + lane];
    const float* rowp = brow + (long)c * 128;
    int ybuf_i = 0;
    float b0[8], c0[8], b1[8], c1[8];
    LOADG(b0, c0, 0)
    LOADG(b1, c1, 1)
    PROCG(b0, c0, 0) LOADG(b0, c0, 2)
    PROCG(b1, c1, 1) LOADG(b1, c1, 3)
    PROCG(b0, c0, 2) LOADG(b0, c0, 4)
    PROCG(b1, c1, 3) LOADG(b1, c1, 5)
    PROCG(b0, c0, 4) LOADG(b0, c0, 6)
    PROCG(b1, c1, 5) LOADG(b1, c1, 7)
    PROCG(b0, c0, 6)
    PROCG(b1, c1, 7)
    ysp[c + lane] = __int_as_float(ybuf_i);
  }
#undef LOADG
#undef PROCG
}

// ---------------------------------------------------------------------------
__global__ void k_yfull(const float* __restrict__ ys, const ushort* __restrict__ xhb,
                        const ushort* __restrict__ xzb, const float* __restrict__ Dp,
                        ushort* __restrict__ yaccb) {
  int i = blockIdx.x * 256 + threadIdx.x;
  int t = i >> 8, d = i & 255;
  float z = bfu(xzb[(long)t * 512 + 256 + d]);
  float sil = z / (1.f + expf(-z));
  float Dd = Dp[d];
  float s = 0.f;
#pragma unroll
  for (int v = 0; v < 4; ++v) {
    int Lp = 512 >> v;
    int b = t >> (9 - v);
    int l = t & (Lp - 1);
    float ysv = ys[(long)v * NT * Di + (long)((b << 8) + d) * Lp + l];
    float xhv = bfu(xhb[(long)v * 524288 + i]);
    s += ysv + Dd * xhv;
  }
  yaccb[i] = bf16bits(s * sil);
}

// ---------------------------------------------------------------------------
// bnrelu + transpose-convert from bf16 H1B; scale/shift inline from SQ.
__global__ __launch_bounds__(256) void k_bnreluT(const ushort* __restrict__ h1b,
                                                 const float* __restrict__ SQ,
                                                 const float* __restrict__ g,
                                                 const float* __restrict__ bb,
                                                 ushort* __restrict__ outT) {
  __shared__ float tile[64][65];
  __shared__ float sc_s[64], sh_s[64];
  int t0 = blockIdx.x * 64, f0 = blockIdx.y * 64, b = blockIdx.z;
  int tid = threadIdx.x;
  if (tid < 64) {
    int f = f0 + tid;
    float mu = SQ[f] * (1.f / NT);
    float var = SQ[256 + f] * (1.f / NT) - mu * mu;
    float sc = g[f] * rsqrtf(var + EPSF);
    sc_s[tid] = sc;
    sh_s[tid] = bb[f] - mu * sc;
  }
  __syncthreads();
  const uint* h1u = (const uint*)h1b;
#pragma unroll
  for (int i = 0; i < 8; ++i) {
    int idx = i * 256 + tid;           // 2048 uints: r(64) x cu(32)
    int r = idx >> 5, cu = idx & 31;
    uint u = h1u[((long)(b * 512 + t0 + r)) * 128 + (f0 >> 1) + cu];
    int c = cu * 2;
    tile[r][c]     = fmaxf(fmaf(bfu((ushort)(u & 0xffff)), sc_s[c], sh_s[c]), 0.f);
    tile[r][c + 1] = fmaxf(fmaf(bfu((ushort)(u >> 16)), sc_s[c + 1], sh_s[c + 1]), 0.f);
  }
  __syncthreads();
  int tc2 = (tid & 31) * 2, fr0 = tid >> 5;
#pragma unroll
  for (int i = 0; i < 8; ++i) {
    int fr = fr0 + i * 8;
    uint u = ((uint)bf16bits(tile[tc2 + 1][fr]) << 16) | bf16bits(tile[tc2][fr]);
    long off = (long)b * 131072 + (long)(f0 + fr) * 512 + t0 + tc2;
    *(uint*)(outT + off) = u;
  }
}

// ---------------------------------------------------------------------------
// Fused fwd DFT + freq op + transpose.
__global__ __launch_bounds__(256) void k_dftfreq(const ushort* __restrict__ CS2B,
                                                 const ushort* __restrict__ H1NTB,
                                                 const float* __restrict__ rd,
                                                 const float* __restrict__ idg,
                                                 const float* __restrict__ rb,
                                                 const float* __restrict__ ib,
                                                 ushort* __restrict__ XRITB) {
  int b = blockIdx.z;
  int lane = threadIdx.x & 63, wid = threadIdx.x >> 6;
  int m0 = blockIdx.y * 64 + wid * 16;   // freq rows 0..511
  int n0 = blockIdx.x * 64;              // feature cols
  const ushort* acrow = CS2B + (long)(m0 + (lane & 15)) * 512 + (lane >> 4) * 8;
  const ushort* asrow = acrow + 512L * 512;
  const ushort* brow = H1NTB + (long)b * 131072 + (long)(n0 + (lane & 15)) * 512 + (lane >> 4) * 8;
  f32x4 aC[4] = {{0.f, 0.f, 0.f, 0.f}, {0.f, 0.f, 0.f, 0.f},
                 {0.f, 0.f, 0.f, 0.f}, {0.f, 0.f, 0.f, 0.f}};
  f32x4 aS[4] = {{0.f, 0.f, 0.f, 0.f}, {0.f, 0.f, 0.f, 0.f},
                 {0.f, 0.f, 0.f, 0.f}, {0.f, 0.f, 0.f, 0.f}};
#pragma unroll 2
  for (int k0 = 0; k0 < 512; k0 += 32) {
    short8 avc = *(const short8*)(acrow + k0);
    short8 avs = *(const short8*)(asrow + k0);
#pragma unroll
    for (int c = 0; c < 4; ++c) {
      short8 bv = *(const short8*)(brow + (long)c * 16 * 512 + k0);
      aC[c] = __builtin_amdgcn_mfma_f32_16x16x32_bf16(avc, bv, aC[c], 0, 0, 0);
      aS[c] = __builtin_amdgcn_mfma_f32_16x16x32_bf16(avs, bv, aS[c], 0, 0, 0);
    }
  }
  int r0 = (lane >> 4) * 4, c0 = lane & 15;
#pragma unroll
  for (int c = 0; c < 4; ++c) {
    int f = n0 + c * 16 + c0;
    float rdv = rd[f], idv = idg[f], rbv = rb[f], ibv = ib[f];
    ushort pr[4], pi[4];
#pragma unroll
    for (int j = 0; j < 4; ++j) {
      float xr = aC[c][j], xi = aS[c][j];
      pr[j] = bf16bits(fmaxf(xr * rdv - xi * idv + rbv, 0.f));
      pi[j] = bf16bits(fmaxf(xi * rdv + xr * idv + ibv, 0.f));
    }
    long base = (long)b * 262144 + (long)f * 1024 + m0 + r0;
    uint2 ur = make_uint2(((uint)pr[1] << 16) | pr[0], ((uint)pr[3] << 16) | pr[2]);
    uint2 ui = make_uint2(((uint)pi[1] << 16) | pi[0], ((uint)pi[3] << 16) | pi[2]);
    *(uint2*)(XRITB + base) = ur;
    *(uint2*)(XRITB + base + 512) = ui;
  }
}

// ---------------------------------------------------------------------------
__global__ __launch_bounds__(256) void k_final(const float* __restrict__ xo,
                                               const ushort* __restrict__ f2b,
                                               const float* __restrict__ SQ,
                                               const float* __restrict__ g,
                                               const float* __restrict__ bb,
                                               float* __restrict__ out) {
  __shared__ float sc_s[128], sh_s[128];
  int tid = threadIdx.x;
  if (tid < 128) {
    float mu = SQ[tid] * (1.f / NT);
    float var = SQ[128 + tid] * (1.f / NT) - mu * mu;
    float sc = g[tid] * rsqrtf(var + EPSF);
    sc_s[tid] = sc;
    sh_s[tid] = bb[tid] - mu * sc;
  }
  __syncthreads();
  int i = blockIdx.x * 256 + tid;
  int c = i & 127;
  out[i] = xo[i] + fmaf(bfu(f2b[i]), sc_s[c], sh_s[c]);
}

// ---------------------------------------------------------------------------
extern "C" void kernel_launch(void* const* d_in, const int* in_sizes, int n_in,
                              void* d_out, int out_size, void* d_ws, size_t ws_size,
                              hipStream_t stream) {
  const float* x         = (const float*)d_in[0];
  const float* ln_w      = (const float*)d_in[1];
  const float* ln_b      = (const float*)d_in[2];
  const float* in_proj_w = (const float*)d_in[3];
  const float* conv_w    = (const float*)d_in[4];
  const float* conv_b    = (const float*)d_in[5];
  const float* x_proj_w  = (const float*)d_in[6];
  const float* dt_proj_w = (const float*)d_in[7];
  const float* dt_proj_b = (const float*)d_in[8];
  const float* A_log     = (const float*)d_in[9];
  const float* D_param   = (const float*)d_in[10];
  const float* out_proj_w= (const float*)d_in[11];
  const float* n1w       = (const float*)d_in[12];
  const float* n1b       = (const float*)d_in[13];
  const float* n2w       = (const float*)d_in[14];
  const float* n2b       = (const float*)d_in[15];
  const float* fc1_w     = (const float*)d_in[16];
  const float* bn1_g     = (const float*)d_in[17];
  const float* bn1_b     = (const float*)d_in[18];
  const float* r_mat     = (const float*)d_in[19];
  const float* i_mat     = (const float*)d_in[20];
  const float* rb        = (const float*)d_in[21];
  const float* ib        = (const float*)d_in[22];
  const float* fc2_w     = (const float*)d_in[23];
  const float* bn2_g     = (const float*)d_in[24];
  const float* bn2_b     = (const float*)d_in[25];
  float* ws  = (float*)d_ws;
  float* out = (float*)d_out;

  k_tables<<<4096, 256, 0, stream>>>(A_log, fc1_w, fc2_w, r_mat, i_mat,
                                     in_proj_w, x_proj_w, dt_proj_w, out_proj_w,
                                     x, ln_w, ln_b, ws);
  // xz = xn @ in_proj_w -> bf16 XZB
  k_gmfma<true><<<dim3(8, 32, 1), 256, 0, stream>>>(
      (const ushort*)(ws + O_XNB), (const ushort*)(ws + O_INPB), ws + O_XZB,
      2048, 512, 128, 0, 0, 0);
  k_conv4<<<2048, 256, 0, stream>>>((const ushort*)(ws + O_XZB), conv_w, conv_b,
                                    (ushort*)(ws + O_XHB));
  // dblx_v = xh_v @ [x_proj | W'] -> fp32 DBLX (N=392)
  k_gmfma<false><<<dim3(7, 32, 4), 256, 0, stream>>>(
      (const ushort*)(ws + O_XHB), (const ushort*)(ws + O_XPB2), ws + O_DBLX,
      2048, 392, 256, 524288L, 0, 802816L);
  k_prep<<<dim3(32, 4), 256, 0, stream>>>(ws + O_DBLX, (const ushort*)(ws + O_XHB),
                                          dt_proj_b, out + 262144,
                                          (uint*)(ws + O_DTDX), ws + O_BCT);
  k_scan<<<3840, 256, 0, stream>>>((const uint*)(ws + O_DTDX), ws + O_BCT,
                                   ws + O_A2, ws + O_YS);
  k_yfull<<<2048, 256, 0, stream>>>(ws + O_YS, (const ushort*)(ws + O_XHB),
                                    (const ushort*)(ws + O_XZB), D_param,
                                    (ushort*)(ws + O_YACCB));
  // x_o = yacc @ out_proj_w -> fp32 XO1
  k_gmfma<false><<<dim3(2, 32, 1), 256, 0, stream>>>(
      (const ushort*)(ws + O_YACCB), (const ushort*)(ws + O_OPB), ws + O_XO1,
      2048, 128, 256, 0, 0, 0);
  k_lndbl<<<512, 256, 0, stream>>>(x, ws + O_XO1, n1w, n1b, n2w, n2b,
                                   ws + O_XO, (ushort*)(ws + O_LN2B));
  // h1 = LN2b @ FC1b^T -> bf16 H1B + SQ1 stats
  k_gmfma_bn<<<dim3(4, 32), 256, 0, stream>>>(
      (const ushort*)(ws + O_LN2B), (const ushort*)(ws + O_FC1B),
      (ushort*)(ws + O_H1B), ws + O_SQ1, 256, 128);
  k_bnreluT<<<dim3(8, 4, 4), 256, 0, stream>>>((const ushort*)(ws + O_H1B),
                                               ws + O_SQ1, bn1_g, bn1_b,
                                               (ushort*)(ws + O_H1NTB));
  // fused fwd DFT + freq + transpose -> XRITB bf16
  k_dftfreq<<<dim3(4, 8, 4), 256, 0, stream>>>(
      (const ushort*)(ws + O_CS2B), (const ushort*)(ws + O_H1NTB),
      ws + O_RD, ws + O_IDG, rb, ib, (ushort*)(ws + O_XRITB));
  // inv DFT: H2b_b = CSIb @ XRITb_b^T -> bf16
  k_gmfma<true><<<dim3(4, 8, 4), 256, 0, stream>>>(
      (const ushort*)(ws + O_CSIB), (const ushort*)(ws + O_XRITB), ws + O_H2B,
      512, 256, 1024, 0, 262144L, 131072L);
  // f2 = H2b @ FC2b^T -> bf16 F2B + SQ2 stats
  k_gmfma_bn<<<dim3(2, 32), 256, 0, stream>>>(
      (const ushort*)(ws + O_H2B), (const ushort*)(ws + O_FC2B),
      (ushort*)(ws + O_F2B), ws + O_SQ2, 128, 256);
  k_final<<<1024, 256, 0, stream>>>(ws + O_XO, (const ushort*)(ws + O_F2B),
                                    ws + O_SQ2, bn2_g, bn2_b, out);
}

// Round 12
// 295.686 us; speedup vs baseline: 1.1762x; 1.1762x over previous
//
#include <hip/hip_runtime.h>
#include <hip/hip_bf16.h>
#include <math.h>

// ---------------------------------------------------------------------------
// SABlock_CrossMamba. R11 = R10 + k_prep re-parallelized: grid (32,7,4)=896
// blocks (was (32,4)=128 -> 5% occupancy, 90us latency-bound). Tasks: 0-3
// DTDX transpose chunks, 4-5 BCT halves, 6 Cm copy. All else unchanged.
// ---------------------------------------------------------------------------

constexpr int NT = 2048;
constexpr int Di = 256;
constexpr float EPSF = 1e-5f;
constexpr float LOG2E = 1.4426950408889634f;
constexpr float ISQ512 = 0.04419417382415922f;  // 1/sqrt(512)

typedef __attribute__((ext_vector_type(8))) short short8;
typedef __attribute__((ext_vector_type(4))) float f32x4;

// ws layout (float offsets, 16B-aligned)
constexpr long O_CS2B  = 0;         // bf16 1024x512
constexpr long O_CSIB  = 262144;    // bf16 512x1024
constexpr long O_A2    = 524288;    // 16384 fl
constexpr long O_FC1B  = 540672;    // bf16 256x128
constexpr long O_FC2B  = 557056;    // bf16 128x256
constexpr long O_INPB  = 573440;    // bf16 512x128
constexpr long O_XPB2  = 606208;    // bf16 448x256 (x_proj 136 | W' 256 | pad)
constexpr long O_OPB   = 663552;    // bf16 128x256
constexpr long O_RD    = 679936;    // 256
constexpr long O_IDG   = 680192;    // 256
constexpr long O_XNB   = 680448;    // bf16 2048x128
constexpr long O_XZB   = 811520;    // bf16 2048x512
constexpr long O_XHB   = 1335808;   // bf16 4x2048x256
constexpr long O_DBLX  = 2384384;   // fp32 4x2048x392 (3211264 fl)
constexpr long O_DTDX  = 5595648;   // uint 4x256x2048 (bf16 dt|dx pair)
constexpr long O_BCT   = 7692800;   // fp32 4x2048x128 (B|C packed)
constexpr long O_YS    = 8741376;   // fp32 4x2048x256
constexpr long O_XO    = 10838528;  // fp32 2048x128
constexpr long O_LN2B  = 11100672;  // bf16 2048x128
constexpr long O_H1B   = 11231744;  // bf16 2048x256
constexpr long O_H1NTB = 11493888;  // bf16 4x256x512
constexpr long O_XRITB = 11756032;  // bf16 4x256x1024 (524288 fl)
constexpr long O_H2B   = 12280320;  // bf16 2048x256
constexpr long O_F2B   = 12542464;  // bf16 2048x128 (131072 fl)
constexpr long O_SQ1   = 12673536;  // 512
constexpr long O_SQ2   = 12674048;  // 256
// Aliases (disjoint lifetimes):
constexpr long O_XO1   = O_XRITB;   // out_proj->lndbl; XRITB written later
constexpr long O_YACCB = O_DBLX;    // yfull->out_proj; DBLX dead after k_prep

__device__ __forceinline__ ushort bf16bits(float v) {
  __hip_bfloat16 h = __float2bfloat16(v);
  return *(ushort*)&h;
}
__device__ __forceinline__ float bfu(ushort u) {
  return __uint_as_float((uint)u << 16);
}

// ---------------------------------------------------------------------------
__global__ __launch_bounds__(256) void k_tables(
    const float* __restrict__ A_log, const float* __restrict__ fc1_w,
    const float* __restrict__ fc2_w, const float* __restrict__ r_mat,
    const float* __restrict__ i_mat, const float* __restrict__ in_proj_w,
    const float* __restrict__ x_proj_w, const float* __restrict__ dt_proj_w,
    const float* __restrict__ out_proj_w,
    const float* __restrict__ x, const float* __restrict__ ln_w,
    const float* __restrict__ ln_b, float* __restrict__ ws) {
  __shared__ float ct[512];
  int tid = threadIdx.x;
  ct[tid]       = __cosf((float)tid * (6.283185307179586f / 512.0f)) * ISQ512;
  ct[tid + 256] = __cosf((float)(tid + 256) * (6.283185307179586f / 512.0f)) * ISQ512;
  __syncthreads();
  __hip_bfloat16* cs2b = (__hip_bfloat16*)(ws + O_CS2B);
  __hip_bfloat16* csib = (__hip_bfloat16*)(ws + O_CSIB);
  int i = blockIdx.x * 256 + tid;   // 1048576 threads
  if (i < 524288) {          // CS2[r][n]: r<512 cos(rn), else -sin((r-512)n)
    int r = i >> 9, n = i & 511;
    float v;
    if (r < 512) v = ct[(r * n) & 511];
    else         v = -ct[((r - 512) * n + 384) & 511];
    cs2b[i] = __float2bfloat16(v);
  } else {                   // CSI[n][kp]: kp<512 cos(n*kp), else -sin(n(kp-512))
    int j = i - 524288;
    int n = j >> 10, kp = j & 1023;
    float v;
    if (kp < 512) v = ct[(n * kp) & 511];
    else          v = -ct[(n * (kp - 512) + 384) & 511];
    csib[j] = __float2bfloat16(v);
  }
  if (i < 16384) ws[O_A2 + i] = -expf(A_log[i]) * LOG2E;
  if (i < 32768) {
    ((__hip_bfloat16*)(ws + O_FC1B))[i] = __float2bfloat16(fc1_w[i]);
    ((__hip_bfloat16*)(ws + O_FC2B))[i] = __float2bfloat16(fc2_w[i]);
  }
  if (i < 65536) {  // INPB[n][k] = in_proj_w[k][n]  (512x128)
    int n = i >> 7, k = i & 127;
    ((__hip_bfloat16*)(ws + O_INPB))[i] = __float2bfloat16(in_proj_w[k * 512 + n]);
  }
  if (i < 114688) {  // XPB2[n][k]: n<136 x_proj^T; 136..391 W'=xp[:, :8]@dtw; pad 0
    int n = i >> 8, k = i & 255;
    float v = 0.f;
    if (n < 136) v = x_proj_w[k * 136 + n];
    else if (n < 392) {
      int d = n - 136;
#pragma unroll
      for (int r = 0; r < 8; ++r) v = fmaf(x_proj_w[k * 136 + r], dt_proj_w[r * 256 + d], v);
    }
    ((__hip_bfloat16*)(ws + O_XPB2))[i] = __float2bfloat16(v);
  }
  if (i >= 131072 && i < 163840) {  // OPB[n][k] = out_proj_w[k][n] (128x256)
    int j = i - 131072;
    int n = j >> 8, k = j & 255;
    ((__hip_bfloat16*)(ws + O_OPB))[j] = __float2bfloat16(out_proj_w[k * 128 + n]);
  }
  if (i < 256) {
    ws[O_RD + i] = r_mat[i * 256 + i];
    ws[O_IDG + i] = i_mat[i * 256 + i];
  }
  if (i < 512) ws[O_SQ1 + i] = 0.f;
  if (i < 256) ws[O_SQ2 + i] = 0.f;
  if (blockIdx.x < 512) {  // ln1, one wave per token
    ushort* outb = (ushort*)(ws + O_XNB);
    int lane = tid & 63;
    int t = (blockIdx.x * 256 + tid) >> 6;
    float v0 = x[t * 128 + lane], v1 = x[t * 128 + 64 + lane];
    float s = v0 + v1, sq = v0 * v0 + v1 * v1;
#pragma unroll
    for (int off = 32; off; off >>= 1) { s += __shfl_xor(s, off); sq += __shfl_xor(sq, off); }
    float mu = s * (1.f / 128.f);
    float rstd = rsqrtf(sq * (1.f / 128.f) - mu * mu + EPSF);
    outb[t * 128 + lane]      = bf16bits((v0 - mu) * rstd * ln_w[lane] + ln_b[lane]);
    outb[t * 128 + 64 + lane] = bf16bits((v1 - mu) * rstd * ln_w[64 + lane] + ln_b[64 + lane]);
  }
}

// ---------------------------------------------------------------------------
__global__ void k_lndbl(const float* __restrict__ x, const float* __restrict__ xo1,
                        const float* __restrict__ w1, const float* __restrict__ b1,
                        const float* __restrict__ w2, const float* __restrict__ b2,
                        float* __restrict__ xo, ushort* __restrict__ ln2b) {
  int lane = threadIdx.x & 63;
  int t = (blockIdx.x * 256 + threadIdx.x) >> 6;
  float u0 = xo1[t * 128 + lane], u1 = xo1[t * 128 + 64 + lane];
  float s = u0 + u1, sq = u0 * u0 + u1 * u1;
#pragma unroll
  for (int off = 32; off; off >>= 1) { s += __shfl_xor(s, off); sq += __shfl_xor(sq, off); }
  float mu = s * (1.f / 128.f);
  float rstd = rsqrtf(sq * (1.f / 128.f) - mu * mu + EPSF);
  float a0 = x[t * 128 + lane]      + (u0 - mu) * rstd * w1[lane] + b1[lane];
  float a1 = x[t * 128 + 64 + lane] + (u1 - mu) * rstd * w1[64 + lane] + b1[64 + lane];
  xo[t * 128 + lane] = a0;
  xo[t * 128 + 64 + lane] = a1;
  s = a0 + a1; sq = a0 * a0 + a1 * a1;
#pragma unroll
  for (int off = 32; off; off >>= 1) { s += __shfl_xor(s, off); sq += __shfl_xor(sq, off); }
  mu = s * (1.f / 128.f);
  rstd = rsqrtf(sq * (1.f / 128.f) - mu * mu + EPSF);
  ln2b[t * 128 + lane]      = bf16bits((a0 - mu) * rstd * w2[lane] + b2[lane]);
  ln2b[t * 128 + 64 + lane] = bf16bits((a1 - mu) * rstd * w2[64 + lane] + b2[64 + lane]);
}

// ---------------------------------------------------------------------------
// bf16 MFMA GEMM: C = A @ Bt^T. Epilogue guards n < N.
template <bool OUTBF16>
__global__ __launch_bounds__(256) void k_gmfma(const ushort* __restrict__ A,
                                               const ushort* __restrict__ Bt,
                                               void* __restrict__ Cv,
                                               int M, int N, int K,
                                               long sA, long sBt, long sC) {
  A += (long)blockIdx.z * sA;
  Bt += (long)blockIdx.z * sBt;
  int lane = threadIdx.x & 63, wid = threadIdx.x >> 6;
  int m0 = blockIdx.y * 64 + wid * 16, n0 = blockIdx.x * 64;
  const ushort* arow = A + (long)(m0 + (lane & 15)) * K + (lane >> 4) * 8;
  const ushort* brow = Bt + (long)(n0 + (lane & 15)) * K + (lane >> 4) * 8;
  f32x4 acc0 = {0.f, 0.f, 0.f, 0.f}, acc1 = acc0, acc2 = acc0, acc3 = acc0;
#pragma unroll 4
  for (int k0 = 0; k0 < K; k0 += 32) {
    short8 av = *(const short8*)(arow + k0);
    short8 b0 = *(const short8*)(brow + k0);
    short8 b1 = *(const short8*)(brow + 16L * K + k0);
    short8 b2 = *(const short8*)(brow + 32L * K + k0);
    short8 b3 = *(const short8*)(brow + 48L * K + k0);
    acc0 = __builtin_amdgcn_mfma_f32_16x16x32_bf16(av, b0, acc0, 0, 0, 0);
    acc1 = __builtin_amdgcn_mfma_f32_16x16x32_bf16(av, b1, acc1, 0, 0, 0);
    acc2 = __builtin_amdgcn_mfma_f32_16x16x32_bf16(av, b2, acc2, 0, 0, 0);
    acc3 = __builtin_amdgcn_mfma_f32_16x16x32_bf16(av, b3, acc3, 0, 0, 0);
  }
  int r0 = (lane >> 4) * 4, c0 = lane & 15;
#pragma unroll
  for (int j = 0; j < 4; ++j) {
    long row = m0 + r0 + j;
    float v[4] = {acc0[j], acc1[j], acc2[j], acc3[j]};
    if (OUTBF16) {
      __hip_bfloat16* C = (__hip_bfloat16*)Cv + blockIdx.z * sC;
#pragma unroll
      for (int c = 0; c < 4; ++c) {
        int n = n0 + c * 16 + c0;
        if (n < N) C[row * N + n] = __float2bfloat16(v[c]);
      }
    } else {
      float* C = (float*)Cv + blockIdx.z * sC;
#pragma unroll
      for (int c = 0; c < 4; ++c) {
        int n = n0 + c * 16 + c0;
        if (n < N) C[row * N + n] = v[c];
      }
    }
  }
}

// bf16 MFMA GEMM + per-column BN partial stats into SQ (atomics). z=1, N%64==0.
__global__ __launch_bounds__(256) void k_gmfma_bn(const ushort* __restrict__ A,
                                                  const ushort* __restrict__ Bt,
                                                  ushort* __restrict__ C,
                                                  float* __restrict__ SQ,
                                                  int N, int K) {
  int lane = threadIdx.x & 63, wid = threadIdx.x >> 6;
  int m0 = blockIdx.y * 64 + wid * 16, n0 = blockIdx.x * 64;
  const ushort* arow = A + (long)(m0 + (lane & 15)) * K + (lane >> 4) * 8;
  const ushort* brow = Bt + (long)(n0 + (lane & 15)) * K + (lane >> 4) * 8;
  f32x4 acc[4] = {{0.f, 0.f, 0.f, 0.f}, {0.f, 0.f, 0.f, 0.f},
                  {0.f, 0.f, 0.f, 0.f}, {0.f, 0.f, 0.f, 0.f}};
#pragma unroll 4
  for (int k0 = 0; k0 < K; k0 += 32) {
    short8 av = *(const short8*)(arow + k0);
#pragma unroll
    for (int c = 0; c < 4; ++c) {
      short8 bv = *(const short8*)(brow + (long)c * 16 * K + k0);
      acc[c] = __builtin_amdgcn_mfma_f32_16x16x32_bf16(av, bv, acc[c], 0, 0, 0);
    }
  }
  int r0 = (lane >> 4) * 4, c0 = lane & 15;
#pragma unroll
  for (int j = 0; j < 4; ++j) {
    long row = m0 + r0 + j;
#pragma unroll
    for (int c = 0; c < 4; ++c)
      C[row * N + n0 + c * 16 + c0] = bf16bits(acc[c][j]);
  }
#pragma unroll
  for (int c = 0; c < 4; ++c) {
    f32x4 v = acc[c];
    float s = v[0] + v[1] + v[2] + v[3];
    float q = v[0] * v[0] + v[1] * v[1] + v[2] * v[2] + v[3] * v[3];
    s += __shfl_xor(s, 16); s += __shfl_xor(s, 32);
    q += __shfl_xor(q, 16); q += __shfl_xor(q, 32);
    if ((lane >> 4) == 0) {
      int n = n0 + c * 16 + c0;
      atomicAdd(&SQ[n], s);
      atomicAdd(&SQ[N + n], q);
    }
  }
}

// ---------------------------------------------------------------------------
// Causal depthwise conv + SiLU, all 4 variants per thread (bf16 in/out).
__global__ void k_conv4(const ushort* __restrict__ xzb, const float* __restrict__ cw,
                        const float* __restrict__ cb, ushort* __restrict__ xhb) {
  int i = blockIdx.x * 256 + threadIdx.x;
  int t = i >> 8, d = i & 255;
  float w0 = cw[d * 4 + 0], w1 = cw[d * 4 + 1], w2 = cw[d * 4 + 2], w3 = cw[d * 4 + 3];
  float bias = cb[d];
  float x0  = bfu(xzb[(long)t * 512 + d]);
  float xm1 = t >= 1 ? bfu(xzb[(long)(t - 1) * 512 + d]) : 0.f;
  float xm2 = t >= 2 ? bfu(xzb[(long)(t - 2) * 512 + d]) : 0.f;
  float xm3 = t >= 3 ? bfu(xzb[(long)(t - 3) * 512 + d]) : 0.f;
  if ((t & 63) >= 3) {
    float s = fmaf(w0, xm3, fmaf(w1, xm2, fmaf(w2, xm1, fmaf(w3, x0, bias))));
    float sil = s / (1.f + expf(-s));
    ushort sb = bf16bits(sil);
#pragma unroll
    for (int v = 0; v < 4; ++v) xhb[v * 524288 + i] = sb;
  } else {
#pragma unroll
    for (int v = 0; v < 4; ++v) {
      int lv = t & ((512 >> v) - 1);
      float s = fmaf(w3, x0, bias);
      if (lv >= 1) s = fmaf(w2, xm1, s);
      if (lv >= 2) s = fmaf(w1, xm2, s);
      if (lv >= 3) s = fmaf(w0, xm3, s);
      float sil = s / (1.f + expf(-s));
      xhb[v * 524288 + i] = bf16bits(sil);
    }
  }
}

// ---------------------------------------------------------------------------
// prep: grid (32 t-tiles, 7 tasks, 4 v) = 896 blocks.
// task 0-3: DTDX 64x64 transpose chunk dc=task; task 4-5: BCT half; task 6: Cm.
__global__ __launch_bounds__(256) void k_prep(const float* __restrict__ dblx,
                                              const ushort* __restrict__ xhb,
                                              const float* __restrict__ dt_b,
                                              float* __restrict__ outC,
                                              uint* __restrict__ DTDX,
                                              float* __restrict__ BCT) {
  int t0 = blockIdx.x * 64, task = blockIdx.y, v = blockIdx.z;
  int tid = threadIdx.x;
  const float* dp = dblx + ((long)v * 2048 + t0) * 392;
  if (task < 4) {
    __shared__ uint tile[64][65];
    int d0 = task * 64;
#pragma unroll
    for (int it = 0; it < 16; ++it) {
      int idx = it * 256 + tid;
      int t = idx >> 6, dl = idx & 63;
      int d = d0 + dl;
      float logit = dp[(long)t * 392 + 136 + d] + dt_b[d];
      float dtv = fmaxf(logit, 0.f) + log1pf(expf(-fabsf(logit)));
      float xv = bfu(xhb[((long)v * 2048 + t0 + t) * 256 + d]);
      tile[t][dl] = ((uint)bf16bits(dtv * xv) << 16) | (uint)bf16bits(dtv);
    }
    __syncthreads();
#pragma unroll
    for (int it = 0; it < 16; ++it) {
      int idx = it * 256 + tid;
      int dl = idx >> 6, t = idx & 63;
      DTDX[((long)(v * 256 + d0 + dl)) * 2048 + t0 + t] = tile[t][dl];
    }
  } else if (task < 6) {
    int j0 = (task - 4) * 64;
    float* bout = BCT + ((long)v * 2048 + t0) * 128;
#pragma unroll
    for (int it = 0; it < 16; ++it) {
      int idx = it * 256 + tid;
      int t = idx >> 6, j = (idx & 63) + j0;
      bout[(long)t * 128 + j] = dp[(long)t * 392 + 8 + j];
    }
  } else {
#pragma unroll
    for (int it = 0; it < 16; ++it) {
      int idx = it * 256 + tid;
      int t = idx >> 6, s = idx & 63;
      outC[(long)v * 131072 + (long)(t0 + t) * 64 + s] = dp[(long)t * 392 + 72 + s];
    }
  }
}

// ---------------------------------------------------------------------------
template <int CTRL>
__device__ __forceinline__ float dpp_add(float x) {
  int t = __builtin_amdgcn_update_dpp(0, __float_as_int(x), CTRL, 0xF, 0xF, true);
  return x + __int_as_float(t);
}

// Selective scan: packed dt/dx, packed B|C rows, writelane scatter.
__global__ __launch_bounds__(256) void k_scan(const uint* __restrict__ DTDX,
                                              const float* __restrict__ BCT,
                                              const float* __restrict__ A2,
                                              float* __restrict__ ys) {
  int lane = threadIdx.x & 63;
  int gwid = (blockIdx.x * 256 + threadIdx.x) >> 6;
  int v, base;
  if (gwid < 1024)      { v = 0; base = 0; }
  else if (gwid < 3072) { v = 1; base = 1024; }
  else if (gwid < 7168) { v = 2; base = 3072; }
  else                  { v = 3; base = 7168; }
  int local = gwid - base;
  int b = local >> 8, d = local & 255;
  int Lp = 512 >> v;
  int t0 = b * Lp;
  const uint* drow = DTDX + ((long)(v * 256 + d)) * 2048 + t0;
  const float* brow = BCT + ((long)(v * 2048 + t0)) * 128;
  float* ysp = ys + (long)v * NT * Di + (long)((b << 8) + d) * Lp;
  float a2 = A2[d * 64 + lane];
  float h = 0.f;

#define LOADG(BB, CC, G)                                                     \
  { const float* rg = rowp + (G) * 1024;                                     \
    _Pragma("unroll") for (int q = 0; q < 8; ++q) {                          \
      BB[q] = rg[q * 128 + lane];                                            \
      CC[q] = rg[q * 128 + 64 + lane];                                       \
    } }
#define PROCG(BB, CC, G)                                                     \
  _Pragma("unroll") for (int q = 0; q < 8; ++q) {                            \
    const int l2 = (G) * 8 + q;                                              \
    uint u = (uint)__builtin_amdgcn_readlane((int)rdx, l2);                  \
    float sdt = __uint_as_float(u << 16);                                    \
    float sdx = __uint_as_float(u & 0xffff0000u);                            \
    float a = __builtin_amdgcn_exp2f(sdt * a2);                              \
    h = fmaf(a, h, sdx * BB[q]);                                             \
    float p = h * CC[q];                                                     \
    p = dpp_add<0x111>(p); p = dpp_add<0x112>(p);                            \
    p = dpp_add<0x114>(p); p = dpp_add<0x118>(p);                            \
    p = dpp_add<0x142>(p); p = dpp_add<0x143>(p);                            \
    int tot = __builtin_amdgcn_readlane(__float_as_int(p), 63);              \
    asm("v_writelane_b32 %0, %1, %2" : "+v"(ybuf_i) : "s"(tot), "i"(l2));    \
  }

  for (int c = 0; c < Lp; c += 64) {
    uint rdx = drow[c + lane];
    const float* rowp = brow + (long)c * 128;
    int ybuf_i = 0;
    float b0[8], c0[8], b1[8], c1[8];
    LOADG(b0, c0, 0)
    LOADG(b1, c1, 1)
    PROCG(b0, c0, 0) LOADG(b0, c0, 2)
    PROCG(b1, c1, 1) LOADG(b1, c1, 3)
    PROCG(b0, c0, 2) LOADG(b0, c0, 4)
    PROCG(b1, c1, 3) LOADG(b1, c1, 5)
    PROCG(b0, c0, 4) LOADG(b0, c0, 6)
    PROCG(b1, c1, 5) LOADG(b1, c1, 7)
    PROCG(b0, c0, 6)
    PROCG(b1, c1, 7)
    ysp[c + lane] = __int_as_float(ybuf_i);
  }
#undef LOADG
#undef PROCG
}

// ---------------------------------------------------------------------------
__global__ void k_yfull(const float* __restrict__ ys, const ushort* __restrict__ xhb,
                        const ushort* __restrict__ xzb, const float* __restrict__ Dp,
                        ushort* __restrict__ yaccb) {
  int i = blockIdx.x * 256 + threadIdx.x;
  int t = i >> 8, d = i & 255;
  float z = bfu(xzb[(long)t * 512 + 256 + d]);
  float sil = z / (1.f + expf(-z));
  float Dd = Dp[d];
  float s = 0.f;
#pragma unroll
  for (int v = 0; v < 4; ++v) {
    int Lp = 512 >> v;
    int b = t >> (9 - v);
    int l = t & (Lp - 1);
    float ysv = ys[(long)v * NT * Di + (long)((b << 8) + d) * Lp + l];
    float xhv = bfu(xhb[(long)v * 524288 + i]);
    s += ysv + Dd * xhv;
  }
  yaccb[i] = bf16bits(s * sil);
}

// ---------------------------------------------------------------------------
// bnrelu + transpose-convert from bf16 H1B; scale/shift inline from SQ.
__global__ __launch_bounds__(256) void k_bnreluT(const ushort* __restrict__ h1b,
                                                 const float* __restrict__ SQ,
                                                 const float* __restrict__ g,
                                                 const float* __restrict__ bb,
                                                 ushort* __restrict__ outT) {
  __shared__ float tile[64][65];
  __shared__ float sc_s[64], sh_s[64];
  int t0 = blockIdx.x * 64, f0 = blockIdx.y * 64, b = blockIdx.z;
  int tid = threadIdx.x;
  if (tid < 64) {
    int f = f0 + tid;
    float mu = SQ[f] * (1.f / NT);
    float var = SQ[256 + f] * (1.f / NT) - mu * mu;
    float sc = g[f] * rsqrtf(var + EPSF);
    sc_s[tid] = sc;
    sh_s[tid] = bb[f] - mu * sc;
  }
  __syncthreads();
  const uint* h1u = (const uint*)h1b;
#pragma unroll
  for (int i = 0; i < 8; ++i) {
    int idx = i * 256 + tid;           // 2048 uints: r(64) x cu(32)
    int r = idx >> 5, cu = idx & 31;
    uint u = h1u[((long)(b * 512 + t0 + r)) * 128 + (f0 >> 1) + cu];
    int c = cu * 2;
    tile[r][c]     = fmaxf(fmaf(bfu((ushort)(u & 0xffff)), sc_s[c], sh_s[c]), 0.f);
    tile[r][c + 1] = fmaxf(fmaf(bfu((ushort)(u >> 16)), sc_s[c + 1], sh_s[c + 1]), 0.f);
  }
  __syncthreads();
  int tc2 = (tid & 31) * 2, fr0 = tid >> 5;
#pragma unroll
  for (int i = 0; i < 8; ++i) {
    int fr = fr0 + i * 8;
    uint u = ((uint)bf16bits(tile[tc2 + 1][fr]) << 16) | bf16bits(tile[tc2][fr]);
    long off = (long)b * 131072 + (long)(f0 + fr) * 512 + t0 + tc2;
    *(uint*)(outT + off) = u;
  }
}

// ---------------------------------------------------------------------------
// Fused fwd DFT + freq op + transpose.
__global__ __launch_bounds__(256) void k_dftfreq(const ushort* __restrict__ CS2B,
                                                 const ushort* __restrict__ H1NTB,
                                                 const float* __restrict__ rd,
                                                 const float* __restrict__ idg,
                                                 const float* __restrict__ rb,
                                                 const float* __restrict__ ib,
                                                 ushort* __restrict__ XRITB) {
  int b = blockIdx.z;
  int lane = threadIdx.x & 63, wid = threadIdx.x >> 6;
  int m0 = blockIdx.y * 64 + wid * 16;   // freq rows 0..511
  int n0 = blockIdx.x * 64;              // feature cols
  const ushort* acrow = CS2B + (long)(m0 + (lane & 15)) * 512 + (lane >> 4) * 8;
  const ushort* asrow = acrow + 512L * 512;
  const ushort* brow = H1NTB + (long)b * 131072 + (long)(n0 + (lane & 15)) * 512 + (lane >> 4) * 8;
  f32x4 aC[4] = {{0.f, 0.f, 0.f, 0.f}, {0.f, 0.f, 0.f, 0.f},
                 {0.f, 0.f, 0.f, 0.f}, {0.f, 0.f, 0.f, 0.f}};
  f32x4 aS[4] = {{0.f, 0.f, 0.f, 0.f}, {0.f, 0.f, 0.f, 0.f},
                 {0.f, 0.f, 0.f, 0.f}, {0.f, 0.f, 0.f, 0.f}};
#pragma unroll 2
  for (int k0 = 0; k0 < 512; k0 += 32) {
    short8 avc = *(const short8*)(acrow + k0);
    short8 avs = *(const short8*)(asrow + k0);
#pragma unroll
    for (int c = 0; c < 4; ++c) {
      short8 bv = *(const short8*)(brow + (long)c * 16 * 512 + k0);
      aC[c] = __builtin_amdgcn_mfma_f32_16x16x32_bf16(avc, bv, aC[c], 0, 0, 0);
      aS[c] = __builtin_amdgcn_mfma_f32_16x16x32_bf16(avs, bv, aS[c], 0, 0, 0);
    }
  }
  int r0 = (lane >> 4) * 4, c0 = lane & 15;
#pragma unroll
  for (int c = 0; c < 4; ++c) {
    int f = n0 + c * 16 + c0;
    float rdv = rd[f], idv = idg[f], rbv = rb[f], ibv = ib[f];
    ushort pr[4], pi[4];
#pragma unroll
    for (int j = 0; j < 4; ++j) {
      float xr = aC[c][j], xi = aS[c][j];
      pr[j] = bf16bits(fmaxf(xr * rdv - xi * idv + rbv, 0.f));
      pi[j] = bf16bits(fmaxf(xi * rdv + xr * idv + ibv, 0.f));
    }
    long base = (long)b * 262144 + (long)f * 1024 + m0 + r0;
    uint2 ur = make_uint2(((uint)pr[1] << 16) | pr[0], ((uint)pr[3] << 16) | pr[2]);
    uint2 ui = make_uint2(((uint)pi[1] << 16) | pi[0], ((uint)pi[3] << 16) | pi[2]);
    *(uint2*)(XRITB + base) = ur;
    *(uint2*)(XRITB + base + 512) = ui;
  }
}

// ---------------------------------------------------------------------------
__global__ __launch_bounds__(256) void k_final(const float* __restrict__ xo,
                                               const ushort* __restrict__ f2b,
                                               const float* __restrict__ SQ,
                                               const float* __restrict__ g,
                                               const float* __restrict__ bb,
                                               float* __restrict__ out) {
  __shared__ float sc_s[128], sh_s[128];
  int tid = threadIdx.x;
  if (tid < 128) {
    float mu = SQ[tid] * (1.f / NT);
    float var = SQ[128 + tid] * (1.f / NT) - mu * mu;
    float sc = g[tid] * rsqrtf(var + EPSF);
    sc_s[tid] = sc;
    sh_s[tid] = bb[tid] - mu * sc;
  }
  __syncthreads();
  int i = blockIdx.x * 256 + tid;
  int c = i & 127;
  out[i] = xo[i] + fmaf(bfu(f2b[i]), sc_s[c], sh_s[c]);
}

// ---------------------------------------------------------------------------
extern "C" void kernel_launch(void* const* d_in, const int* in_sizes, int n_in,
                              void* d_out, int out_size, void* d_ws, size_t ws_size,
                              hipStream_t stream) {
  const float* x         = (const float*)d_in[0];
  const float* ln_w      = (const float*)d_in[1];
  const float* ln_b      = (const float*)d_in[2];
  const float* in_proj_w = (const float*)d_in[3];
  const float* conv_w    = (const float*)d_in[4];
  const float* conv_b    = (const float*)d_in[5];
  const float* x_proj_w  = (const float*)d_in[6];
  const float* dt_proj_w = (const float*)d_in[7];
  const float* dt_proj_b = (const float*)d_in[8];
  const float* A_log     = (const float*)d_in[9];
  const float* D_param   = (const float*)d_in[10];
  const float* out_proj_w= (const float*)d_in[11];
  const float* n1w       = (const float*)d_in[12];
  const float* n1b       = (const float*)d_in[13];
  const float* n2w       = (const float*)d_in[14];
  const float* n2b       = (const float*)d_in[15];
  const float* fc1_w     = (const float*)d_in[16];
  const float* bn1_g     = (const float*)d_in[17];
  const float* bn1_b     = (const float*)d_in[18];
  const float* r_mat     = (const float*)d_in[19];
  const float* i_mat     = (const float*)d_in[20];
  const float* rb        = (const float*)d_in[21];
  const float* ib        = (const float*)d_in[22];
  const float* fc2_w     = (const float*)d_in[23];
  const float* bn2_g     = (const float*)d_in[24];
  const float* bn2_b     = (const float*)d_in[25];
  float* ws  = (float*)d_ws;
  float* out = (float*)d_out;

  k_tables<<<4096, 256, 0, stream>>>(A_log, fc1_w, fc2_w, r_mat, i_mat,
                                     in_proj_w, x_proj_w, dt_proj_w, out_proj_w,
                                     x, ln_w, ln_b, ws);
  // xz = xn @ in_proj_w -> bf16 XZB
  k_gmfma<true><<<dim3(8, 32, 1), 256, 0, stream>>>(
      (const ushort*)(ws + O_XNB), (const ushort*)(ws + O_INPB), ws + O_XZB,
      2048, 512, 128, 0, 0, 0);
  k_conv4<<<2048, 256, 0, stream>>>((const ushort*)(ws + O_XZB), conv_w, conv_b,
                                    (ushort*)(ws + O_XHB));
  // dblx_v = xh_v @ [x_proj | W'] -> fp32 DBLX (N=392)
  k_gmfma<false><<<dim3(7, 32, 4), 256, 0, stream>>>(
      (const ushort*)(ws + O_XHB), (const ushort*)(ws + O_XPB2), ws + O_DBLX,
      2048, 392, 256, 524288L, 0, 802816L);
  k_prep<<<dim3(32, 7, 4), 256, 0, stream>>>(ws + O_DBLX, (const ushort*)(ws + O_XHB),
                                             dt_proj_b, out + 262144,
                                             (uint*)(ws + O_DTDX), ws + O_BCT);
  k_scan<<<3840, 256, 0, stream>>>((const uint*)(ws + O_DTDX), ws + O_BCT,
                                   ws + O_A2, ws + O_YS);
  k_yfull<<<2048, 256, 0, stream>>>(ws + O_YS, (const ushort*)(ws + O_XHB),
                                    (const ushort*)(ws + O_XZB), D_param,
                                    (ushort*)(ws + O_YACCB));
  // x_o = yacc @ out_proj_w -> fp32 XO1
  k_gmfma<false><<<dim3(2, 32, 1), 256, 0, stream>>>(
      (const ushort*)(ws + O_YACCB), (const ushort*)(ws + O_OPB), ws + O_XO1,
      2048, 128, 256, 0, 0, 0);
  k_lndbl<<<512, 256, 0, stream>>>(x, ws + O_XO1, n1w, n1b, n2w, n2b,
                                   ws + O_XO, (ushort*)(ws + O_LN2B));
  // h1 = LN2b @ FC1b^T -> bf16 H1B + SQ1 stats
  k_gmfma_bn<<<dim3(4, 32), 256, 0, stream>>>(
      (const ushort*)(ws + O_LN2B), (const ushort*)(ws + O_FC1B),
      (ushort*)(ws + O_H1B), ws + O_SQ1, 256, 128);
  k_bnreluT<<<dim3(8, 4, 4), 256, 0, stream>>>((const ushort*)(ws + O_H1B),
                                               ws + O_SQ1, bn1_g, bn1_b,
                                               (ushort*)(ws + O_H1NTB));
  // fused fwd DFT + freq + transpose -> XRITB bf16
  k_dftfreq<<<dim3(4, 8, 4), 256, 0, stream>>>(
      (const ushort*)(ws + O_CS2B), (const ushort*)(ws + O_H1NTB),
      ws + O_RD, ws + O_IDG, rb, ib, (ushort*)(ws + O_XRITB));
  // inv DFT: H2b_b = CSIb @ XRITb_b^T -> bf16
  k_gmfma<true><<<dim3(4, 8, 4), 256, 0, stream>>>(
      (const ushort*)(ws + O_CSIB), (const ushort*)(ws + O_XRITB), ws + O_H2B,
      512, 256, 1024, 0, 262144L, 131072L);
  // f2 = H2b @ FC2b^T -> bf16 F2B + SQ2 stats
  k_gmfma_bn<<<dim3(2, 32), 256, 0, stream>>>(
      (const ushort*)(ws + O_H2B), (const ushort*)(ws + O_FC2B),
      (ushort*)(ws + O_F2B), ws + O_SQ2, 128, 256);
  k_final<<<1024, 256, 0, stream>>>(ws + O_XO, (const ushort*)(ws + O_F2B),
                                    ws + O_SQ2, bn2_g, bn2_b, out);
}

// Round 13
// 287.496 us; speedup vs baseline: 1.2097x; 1.0285x over previous
//
#include <hip/hip_runtime.h>
#include <hip/hip_bf16.h>
#include <math.h>

// ---------------------------------------------------------------------------
// SABlock_CrossMamba. R13 = R12 with W' fold REVERTED (it tripled the x_proj
// GEMM: N=392 vs 136, +1.07GF, +8MB traffic -> ate all fusion savings).
// x_proj GEMM N=136; k_prep recomputes dt (8 FMA, LDS-staged weights).
// Scan (68us, 82% VALUBusy) unchanged - near issue floor.
// ---------------------------------------------------------------------------

constexpr int NT = 2048;
constexpr int Di = 256;
constexpr float EPSF = 1e-5f;
constexpr float LOG2E = 1.4426950408889634f;
constexpr float ISQ512 = 0.04419417382415922f;  // 1/sqrt(512)

typedef __attribute__((ext_vector_type(8))) short short8;
typedef __attribute__((ext_vector_type(4))) float f32x4;

// ws layout (float offsets, 16B-aligned)
constexpr long O_CS2B  = 0;         // bf16 1024x512
constexpr long O_CSIB  = 262144;    // bf16 512x1024
constexpr long O_A2    = 524288;    // 16384 fl
constexpr long O_FC1B  = 540672;    // bf16 256x128
constexpr long O_FC2B  = 557056;    // bf16 128x256
constexpr long O_INPB  = 573440;    // bf16 512x128
constexpr long O_XPB   = 606208;    // bf16 192x256 (x_proj^T, pad n>=136)
constexpr long O_OPB   = 630784;    // bf16 128x256
constexpr long O_RD    = 647168;    // 256
constexpr long O_IDG   = 647424;    // 256
constexpr long O_XNB   = 647680;    // bf16 2048x128
constexpr long O_XZB   = 778752;    // bf16 2048x512
constexpr long O_XHB   = 1303040;   // bf16 4x2048x256
constexpr long O_DBL   = 2351616;   // fp32 4x2048x136 (1114112 fl)
constexpr long O_DTDX  = 3465728;   // uint 4x256x2048 (bf16 dt|dx pair)
constexpr long O_BCT   = 5562880;   // fp32 4x2048x128 (B|C packed)
constexpr long O_YS    = 6611456;   // fp32 4x2048x256
constexpr long O_XO    = 8708608;   // fp32 2048x128
constexpr long O_LN2B  = 8970752;   // bf16 2048x128
constexpr long O_H1B   = 9101824;   // bf16 2048x256
constexpr long O_H1NTB = 9363968;   // bf16 4x256x512
constexpr long O_XRITB = 9626112;   // bf16 4x256x1024 (524288 fl)
constexpr long O_H2B   = 10150400;  // bf16 2048x256
constexpr long O_F2B   = 10412544;  // bf16 2048x128
constexpr long O_SQ1   = 10543616;  // 512
constexpr long O_SQ2   = 10544128;  // 256
// Aliases (disjoint lifetimes):
constexpr long O_XO1   = O_XRITB;   // out_proj->lndbl; XRITB written later
constexpr long O_YACCB = O_DBL;     // yfull->out_proj; DBL dead after k_prep

__device__ __forceinline__ ushort bf16bits(float v) {
  __hip_bfloat16 h = __float2bfloat16(v);
  return *(ushort*)&h;
}
__device__ __forceinline__ float bfu(ushort u) {
  return __uint_as_float((uint)u << 16);
}

// ---------------------------------------------------------------------------
__global__ __launch_bounds__(256) void k_tables(
    const float* __restrict__ A_log, const float* __restrict__ fc1_w,
    const float* __restrict__ fc2_w, const float* __restrict__ r_mat,
    const float* __restrict__ i_mat, const float* __restrict__ in_proj_w,
    const float* __restrict__ x_proj_w, const float* __restrict__ out_proj_w,
    const float* __restrict__ x, const float* __restrict__ ln_w,
    const float* __restrict__ ln_b, float* __restrict__ ws) {
  __shared__ float ct[512];
  int tid = threadIdx.x;
  ct[tid]       = __cosf((float)tid * (6.283185307179586f / 512.0f)) * ISQ512;
  ct[tid + 256] = __cosf((float)(tid + 256) * (6.283185307179586f / 512.0f)) * ISQ512;
  __syncthreads();
  __hip_bfloat16* cs2b = (__hip_bfloat16*)(ws + O_CS2B);
  __hip_bfloat16* csib = (__hip_bfloat16*)(ws + O_CSIB);
  int i = blockIdx.x * 256 + tid;   // 1048576 threads
  if (i < 524288) {          // CS2[r][n]: r<512 cos(rn), else -sin((r-512)n)
    int r = i >> 9, n = i & 511;
    float v;
    if (r < 512) v = ct[(r * n) & 511];
    else         v = -ct[((r - 512) * n + 384) & 511];
    cs2b[i] = __float2bfloat16(v);
  } else {                   // CSI[n][kp]: kp<512 cos(n*kp), else -sin(n(kp-512))
    int j = i - 524288;
    int n = j >> 10, kp = j & 1023;
    float v;
    if (kp < 512) v = ct[(n * kp) & 511];
    else          v = -ct[(n * (kp - 512) + 384) & 511];
    csib[j] = __float2bfloat16(v);
  }
  if (i < 16384) ws[O_A2 + i] = -expf(A_log[i]) * LOG2E;
  if (i < 32768) {
    ((__hip_bfloat16*)(ws + O_FC1B))[i] = __float2bfloat16(fc1_w[i]);
    ((__hip_bfloat16*)(ws + O_FC2B))[i] = __float2bfloat16(fc2_w[i]);
  }
  if (i < 65536) {  // INPB[n][k] = in_proj_w[k][n]  (512x128)
    int n = i >> 7, k = i & 127;
    ((__hip_bfloat16*)(ws + O_INPB))[i] = __float2bfloat16(in_proj_w[k * 512 + n]);
  }
  if (i < 49152) {  // XPB[n][k] = x_proj_w[k][n], zero pad n>=136 (192x256)
    int n = i >> 8, k = i & 255;
    float v = (n < 136) ? x_proj_w[k * 136 + n] : 0.f;
    ((__hip_bfloat16*)(ws + O_XPB))[i] = __float2bfloat16(v);
  }
  if (i >= 65536 && i < 98304) {  // OPB[n][k] = out_proj_w[k][n] (128x256)
    int j = i - 65536;
    int n = j >> 8, k = j & 255;
    ((__hip_bfloat16*)(ws + O_OPB))[j] = __float2bfloat16(out_proj_w[k * 128 + n]);
  }
  if (i < 256) {
    ws[O_RD + i] = r_mat[i * 256 + i];
    ws[O_IDG + i] = i_mat[i * 256 + i];
  }
  if (i < 512) ws[O_SQ1 + i] = 0.f;
  if (i < 256) ws[O_SQ2 + i] = 0.f;
  if (blockIdx.x < 512) {  // ln1, one wave per token
    ushort* outb = (ushort*)(ws + O_XNB);
    int lane = tid & 63;
    int t = (blockIdx.x * 256 + tid) >> 6;
    float v0 = x[t * 128 + lane], v1 = x[t * 128 + 64 + lane];
    float s = v0 + v1, sq = v0 * v0 + v1 * v1;
#pragma unroll
    for (int off = 32; off; off >>= 1) { s += __shfl_xor(s, off); sq += __shfl_xor(sq, off); }
    float mu = s * (1.f / 128.f);
    float rstd = rsqrtf(sq * (1.f / 128.f) - mu * mu + EPSF);
    outb[t * 128 + lane]      = bf16bits((v0 - mu) * rstd * ln_w[lane] + ln_b[lane]);
    outb[t * 128 + 64 + lane] = bf16bits((v1 - mu) * rstd * ln_w[64 + lane] + ln_b[64 + lane]);
  }
}

// ---------------------------------------------------------------------------
__global__ void k_lndbl(const float* __restrict__ x, const float* __restrict__ xo1,
                        const float* __restrict__ w1, const float* __restrict__ b1,
                        const float* __restrict__ w2, const float* __restrict__ b2,
                        float* __restrict__ xo, ushort* __restrict__ ln2b) {
  int lane = threadIdx.x & 63;
  int t = (blockIdx.x * 256 + threadIdx.x) >> 6;
  float u0 = xo1[t * 128 + lane], u1 = xo1[t * 128 + 64 + lane];
  float s = u0 + u1, sq = u0 * u0 + u1 * u1;
#pragma unroll
  for (int off = 32; off; off >>= 1) { s += __shfl_xor(s, off); sq += __shfl_xor(sq, off); }
  float mu = s * (1.f / 128.f);
  float rstd = rsqrtf(sq * (1.f / 128.f) - mu * mu + EPSF);
  float a0 = x[t * 128 + lane]      + (u0 - mu) * rstd * w1[lane] + b1[lane];
  float a1 = x[t * 128 + 64 + lane] + (u1 - mu) * rstd * w1[64 + lane] + b1[64 + lane];
  xo[t * 128 + lane] = a0;
  xo[t * 128 + 64 + lane] = a1;
  s = a0 + a1; sq = a0 * a0 + a1 * a1;
#pragma unroll
  for (int off = 32; off; off >>= 1) { s += __shfl_xor(s, off); sq += __shfl_xor(sq, off); }
  mu = s * (1.f / 128.f);
  rstd = rsqrtf(sq * (1.f / 128.f) - mu * mu + EPSF);
  ln2b[t * 128 + lane]      = bf16bits((a0 - mu) * rstd * w2[lane] + b2[lane]);
  ln2b[t * 128 + 64 + lane] = bf16bits((a1 - mu) * rstd * w2[64 + lane] + b2[64 + lane]);
}

// ---------------------------------------------------------------------------
// bf16 MFMA GEMM: C = A @ Bt^T. Epilogue guards n < N.
template <bool OUTBF16>
__global__ __launch_bounds__(256) void k_gmfma(const ushort* __restrict__ A,
                                               const ushort* __restrict__ Bt,
                                               void* __restrict__ Cv,
                                               int M, int N, int K,
                                               long sA, long sBt, long sC) {
  A += (long)blockIdx.z * sA;
  Bt += (long)blockIdx.z * sBt;
  int lane = threadIdx.x & 63, wid = threadIdx.x >> 6;
  int m0 = blockIdx.y * 64 + wid * 16, n0 = blockIdx.x * 64;
  const ushort* arow = A + (long)(m0 + (lane & 15)) * K + (lane >> 4) * 8;
  const ushort* brow = Bt + (long)(n0 + (lane & 15)) * K + (lane >> 4) * 8;
  f32x4 acc0 = {0.f, 0.f, 0.f, 0.f}, acc1 = acc0, acc2 = acc0, acc3 = acc0;
#pragma unroll 4
  for (int k0 = 0; k0 < K; k0 += 32) {
    short8 av = *(const short8*)(arow + k0);
    short8 b0 = *(const short8*)(brow + k0);
    short8 b1 = *(const short8*)(brow + 16L * K + k0);
    short8 b2 = *(const short8*)(brow + 32L * K + k0);
    short8 b3 = *(const short8*)(brow + 48L * K + k0);
    acc0 = __builtin_amdgcn_mfma_f32_16x16x32_bf16(av, b0, acc0, 0, 0, 0);
    acc1 = __builtin_amdgcn_mfma_f32_16x16x32_bf16(av, b1, acc1, 0, 0, 0);
    acc2 = __builtin_amdgcn_mfma_f32_16x16x32_bf16(av, b2, acc2, 0, 0, 0);
    acc3 = __builtin_amdgcn_mfma_f32_16x16x32_bf16(av, b3, acc3, 0, 0, 0);
  }
  int r0 = (lane >> 4) * 4, c0 = lane & 15;
#pragma unroll
  for (int j = 0; j < 4; ++j) {
    long row = m0 + r0 + j;
    float v[4] = {acc0[j], acc1[j], acc2[j], acc3[j]};
    if (OUTBF16) {
      __hip_bfloat16* C = (__hip_bfloat16*)Cv + blockIdx.z * sC;
#pragma unroll
      for (int c = 0; c < 4; ++c) {
        int n = n0 + c * 16 + c0;
        if (n < N) C[row * N + n] = __float2bfloat16(v[c]);
      }
    } else {
      float* C = (float*)Cv + blockIdx.z * sC;
#pragma unroll
      for (int c = 0; c < 4; ++c) {
        int n = n0 + c * 16 + c0;
        if (n < N) C[row * N + n] = v[c];
      }
    }
  }
}

// bf16 MFMA GEMM + per-column BN partial stats into SQ (atomics). z=1, N%64==0.
__global__ __launch_bounds__(256) void k_gmfma_bn(const ushort* __restrict__ A,
                                                  const ushort* __restrict__ Bt,
                                                  ushort* __restrict__ C,
                                                  float* __restrict__ SQ,
                                                  int N, int K) {
  int lane = threadIdx.x & 63, wid = threadIdx.x >> 6;
  int m0 = blockIdx.y * 64 + wid * 16, n0 = blockIdx.x * 64;
  const ushort* arow = A + (long)(m0 + (lane & 15)) * K + (lane >> 4) * 8;
  const ushort* brow = Bt + (long)(n0 + (lane & 15)) * K + (lane >> 4) * 8;
  f32x4 acc[4] = {{0.f, 0.f, 0.f, 0.f}, {0.f, 0.f, 0.f, 0.f},
                  {0.f, 0.f, 0.f, 0.f}, {0.f, 0.f, 0.f, 0.f}};
#pragma unroll 4
  for (int k0 = 0; k0 < K; k0 += 32) {
    short8 av = *(const short8*)(arow + k0);
#pragma unroll
    for (int c = 0; c < 4; ++c) {
      short8 bv = *(const short8*)(brow + (long)c * 16 * K + k0);
      acc[c] = __builtin_amdgcn_mfma_f32_16x16x32_bf16(av, bv, acc[c], 0, 0, 0);
    }
  }
  int r0 = (lane >> 4) * 4, c0 = lane & 15;
#pragma unroll
  for (int j = 0; j < 4; ++j) {
    long row = m0 + r0 + j;
#pragma unroll
    for (int c = 0; c < 4; ++c)
      C[row * N + n0 + c * 16 + c0] = bf16bits(acc[c][j]);
  }
#pragma unroll
  for (int c = 0; c < 4; ++c) {
    f32x4 v = acc[c];
    float s = v[0] + v[1] + v[2] + v[3];
    float q = v[0] * v[0] + v[1] * v[1] + v[2] * v[2] + v[3] * v[3];
    s += __shfl_xor(s, 16); s += __shfl_xor(s, 32);
    q += __shfl_xor(q, 16); q += __shfl_xor(q, 32);
    if ((lane >> 4) == 0) {
      int n = n0 + c * 16 + c0;
      atomicAdd(&SQ[n], s);
      atomicAdd(&SQ[N + n], q);
    }
  }
}

// ---------------------------------------------------------------------------
// Causal depthwise conv + SiLU, all 4 variants per thread (bf16 in/out).
__global__ void k_conv4(const ushort* __restrict__ xzb, const float* __restrict__ cw,
                        const float* __restrict__ cb, ushort* __restrict__ xhb) {
  int i = blockIdx.x * 256 + threadIdx.x;
  int t = i >> 8, d = i & 255;
  float w0 = cw[d * 4 + 0], w1 = cw[d * 4 + 1], w2 = cw[d * 4 + 2], w3 = cw[d * 4 + 3];
  float bias = cb[d];
  float x0  = bfu(xzb[(long)t * 512 + d]);
  float xm1 = t >= 1 ? bfu(xzb[(long)(t - 1) * 512 + d]) : 0.f;
  float xm2 = t >= 2 ? bfu(xzb[(long)(t - 2) * 512 + d]) : 0.f;
  float xm3 = t >= 3 ? bfu(xzb[(long)(t - 3) * 512 + d]) : 0.f;
  if ((t & 63) >= 3) {
    float s = fmaf(w0, xm3, fmaf(w1, xm2, fmaf(w2, xm1, fmaf(w3, x0, bias))));
    float sil = s / (1.f + expf(-s));
    ushort sb = bf16bits(sil);
#pragma unroll
    for (int v = 0; v < 4; ++v) xhb[v * 524288 + i] = sb;
  } else {
#pragma unroll
    for (int v = 0; v < 4; ++v) {
      int lv = t & ((512 >> v) - 1);
      float s = fmaf(w3, x0, bias);
      if (lv >= 1) s = fmaf(w2, xm1, s);
      if (lv >= 2) s = fmaf(w1, xm2, s);
      if (lv >= 3) s = fmaf(w0, xm3, s);
      float sil = s / (1.f + expf(-s));
      xhb[v * 524288 + i] = bf16bits(sil);
    }
  }
}

// ---------------------------------------------------------------------------
// prep: grid (32 t-tiles, 6 tasks, 4 v) = 768 blocks.
// task 0-3: DTDX 64x64 chunk (dt computed via 8 FMA from dbl cols 0..7);
// task 4: BCT copy; task 5: Cm copy.  DBL row stride = 136 fl (544B, 16B ok).
__global__ __launch_bounds__(256) void k_prep(const float* __restrict__ dbl,
                                              const ushort* __restrict__ xhb,
                                              const float* __restrict__ dtw,
                                              const float* __restrict__ dt_b,
                                              float* __restrict__ outC,
                                              uint* __restrict__ DTDX,
                                              float* __restrict__ BCT) {
  int t0 = blockIdx.x * 64, task = blockIdx.y, v = blockIdx.z;
  int tid = threadIdx.x;
  const float* dp = dbl + ((long)v * 2048 + t0) * 136;
  if (task < 4) {
    __shared__ float r8T[8][64];
    __shared__ float wt[8][64];
    __shared__ uint tile[64][65];
    int d0 = task * 64;
    if (tid < 128) {
      int t = tid >> 1, half = tid & 1;
      float4 q = *(const float4*)&dp[(long)t * 136 + half * 4];
      r8T[half * 4 + 0][t] = q.x; r8T[half * 4 + 1][t] = q.y;
      r8T[half * 4 + 2][t] = q.z; r8T[half * 4 + 3][t] = q.w;
    } else {
      int idx = tid - 128;
      int r = idx >> 4, dl4 = (idx & 15) * 4;
      float4 q = *(const float4*)&dtw[r * 256 + d0 + dl4];
      wt[r][dl4] = q.x; wt[r][dl4 + 1] = q.y; wt[r][dl4 + 2] = q.z; wt[r][dl4 + 3] = q.w;
    }
    __syncthreads();
#pragma unroll
    for (int it = 0; it < 16; ++it) {
      int idx = it * 256 + tid;
      int t = idx >> 6, dl = idx & 63;
      int d = d0 + dl;
      float s = dt_b[d];
#pragma unroll
      for (int r = 0; r < 8; ++r) s = fmaf(r8T[r][t], wt[r][dl], s);
      float dtv = fmaxf(s, 0.f) + log1pf(expf(-fabsf(s)));
      float xv = bfu(xhb[((long)v * 2048 + t0 + t) * 256 + d]);
      tile[t][dl] = ((uint)bf16bits(dtv * xv) << 16) | (uint)bf16bits(dtv);
    }
    __syncthreads();
#pragma unroll
    for (int it = 0; it < 16; ++it) {
      int idx = it * 256 + tid;
      int dl = idx >> 6, t = idx & 63;
      DTDX[((long)(v * 256 + d0 + dl)) * 2048 + t0 + t] = tile[t][dl];
    }
  } else if (task == 4) {
    float* bout = BCT + ((long)v * 2048 + t0) * 128;
#pragma unroll
    for (int it = 0; it < 32; ++it) {
      int idx = it * 256 + tid;
      int t = idx >> 7, j = idx & 127;
      bout[idx] = dp[(long)t * 136 + 8 + j];
    }
  } else {
#pragma unroll
    for (int it = 0; it < 16; ++it) {
      int idx = it * 256 + tid;
      int t = idx >> 6, s = idx & 63;
      outC[(long)v * 131072 + (long)(t0 + t) * 64 + s] = dp[(long)t * 136 + 72 + s];
    }
  }
}

// ---------------------------------------------------------------------------
template <int CTRL>
__device__ __forceinline__ float dpp_add(float x) {
  int t = __builtin_amdgcn_update_dpp(0, __float_as_int(x), CTRL, 0xF, 0xF, true);
  return x + __int_as_float(t);
}

// Selective scan: packed dt/dx, packed B|C rows, writelane scatter.
__global__ __launch_bounds__(256) void k_scan(const uint* __restrict__ DTDX,
                                              const float* __restrict__ BCT,
                                              const float* __restrict__ A2,
                                              float* __restrict__ ys) {
  int lane = threadIdx.x & 63;
  int gwid = (blockIdx.x * 256 + threadIdx.x) >> 6;
  int v, base;
  if (gwid < 1024)      { v = 0; base = 0; }
  else if (gwid < 3072) { v = 1; base = 1024; }
  else if (gwid < 7168) { v = 2; base = 3072; }
  else                  { v = 3; base = 7168; }
  int local = gwid - base;
  int b = local >> 8, d = local & 255;
  int Lp = 512 >> v;
  int t0 = b * Lp;
  const uint* drow = DTDX + ((long)(v * 256 + d)) * 2048 + t0;
  const float* brow = BCT + ((long)(v * 2048 + t0)) * 128;
  float* ysp = ys + (long)v * NT * Di + (long)((b << 8) + d) * Lp;
  float a2 = A2[d * 64 + lane];
  float h = 0.f;

#define LOADG(BB, CC, G)                                                     \
  { const float* rg = rowp + (G) * 1024;                                     \
    _Pragma("unroll") for (int q = 0; q < 8; ++q) {                          \
      BB[q] = rg[q * 128 + lane];                                            \
      CC[q] = rg[q * 128 + 64 + lane];                                       \
    } }
#define PROCG(BB, CC, G)                                                     \
  _Pragma("unroll") for (int q = 0; q < 8; ++q) {                            \
    const int l2 = (G) * 8 + q;                                              \
    uint u = (uint)__builtin_amdgcn_readlane((int)rdx, l2);                  \
    float sdt = __uint_as_float(u << 16);                                    \
    float sdx = __uint_as_float(u & 0xffff0000u);                            \
    float a = __builtin_amdgcn_exp2f(sdt * a2);                              \
    h = fmaf(a, h, sdx * BB[q]);                                             \
    float p = h * CC[q];                                                     \
    p = dpp_add<0x111>(p); p = dpp_add<0x112>(p);                            \
    p = dpp_add<0x114>(p); p = dpp_add<0x118>(p);                            \
    p = dpp_add<0x142>(p); p = dpp_add<0x143>(p);                            \
    int tot = __builtin_amdgcn_readlane(__float_as_int(p), 63);              \
    asm("v_writelane_b32 %0, %1, %2" : "+v"(ybuf_i) : "s"(tot), "i"(l2));    \
  }

  for (int c = 0; c < Lp; c += 64) {
    uint rdx = drow[c + lane];
    const float* rowp = brow + (long)c * 128;
    int ybuf_i = 0;
    float b0[8], c0[8], b1[8], c1[8];
    LOADG(b0, c0, 0)
    LOADG(b1, c1, 1)
    PROCG(b0, c0, 0) LOADG(b0, c0, 2)
    PROCG(b1, c1, 1) LOADG(b1, c1, 3)
    PROCG(b0, c0, 2) LOADG(b0, c0, 4)
    PROCG(b1, c1, 3) LOADG(b1, c1, 5)
    PROCG(b0, c0, 4) LOADG(b0, c0, 6)
    PROCG(b1, c1, 5) LOADG(b1, c1, 7)
    PROCG(b0, c0, 6)
    PROCG(b1, c1, 7)
    ysp[c + lane] = __int_as_float(ybuf_i);
  }
#undef LOADG
#undef PROCG
}

// ---------------------------------------------------------------------------
__global__ void k_yfull(const float* __restrict__ ys, const ushort* __restrict__ xhb,
                        const ushort* __restrict__ xzb, const float* __restrict__ Dp,
                        ushort* __restrict__ yaccb) {
  int i = blockIdx.x * 256 + threadIdx.x;
  int t = i >> 8, d = i & 255;
  float z = bfu(xzb[(long)t * 512 + 256 + d]);
  float sil = z / (1.f + expf(-z));
  float Dd = Dp[d];
  float s = 0.f;
#pragma unroll
  for (int v = 0; v < 4; ++v) {
    int Lp = 512 >> v;
    int b = t >> (9 - v);
    int l = t & (Lp - 1);
    float ysv = ys[(long)v * NT * Di + (long)((b << 8) + d) * Lp + l];
    float xhv = bfu(xhb[(long)v * 524288 + i]);
    s += ysv + Dd * xhv;
  }
  yaccb[i] = bf16bits(s * sil);
}

// ---------------------------------------------------------------------------
// bnrelu + transpose-convert from bf16 H1B; scale/shift inline from SQ.
__global__ __launch_bounds__(256) void k_bnreluT(const ushort* __restrict__ h1b,
                                                 const float* __restrict__ SQ,
                                                 const float* __restrict__ g,
                                                 const float* __restrict__ bb,
                                                 ushort* __restrict__ outT) {
  __shared__ float tile[64][65];
  __shared__ float sc_s[64], sh_s[64];
  int t0 = blockIdx.x * 64, f0 = blockIdx.y * 64, b = blockIdx.z;
  int tid = threadIdx.x;
  if (tid < 64) {
    int f = f0 + tid;
    float mu = SQ[f] * (1.f / NT);
    float var = SQ[256 + f] * (1.f / NT) - mu * mu;
    float sc = g[f] * rsqrtf(var + EPSF);
    sc_s[tid] = sc;
    sh_s[tid] = bb[f] - mu * sc;
  }
  __syncthreads();
  const uint* h1u = (const uint*)h1b;
#pragma unroll
  for (int i = 0; i < 8; ++i) {
    int idx = i * 256 + tid;           // 2048 uints: r(64) x cu(32)
    int r = idx >> 5, cu = idx & 31;
    uint u = h1u[((long)(b * 512 + t0 + r)) * 128 + (f0 >> 1) + cu];
    int c = cu * 2;
    tile[r][c]     = fmaxf(fmaf(bfu((ushort)(u & 0xffff)), sc_s[c], sh_s[c]), 0.f);
    tile[r][c + 1] = fmaxf(fmaf(bfu((ushort)(u >> 16)), sc_s[c + 1], sh_s[c + 1]), 0.f);
  }
  __syncthreads();
  int tc2 = (tid & 31) * 2, fr0 = tid >> 5;
#pragma unroll
  for (int i = 0; i < 8; ++i) {
    int fr = fr0 + i * 8;
    uint u = ((uint)bf16bits(tile[tc2 + 1][fr]) << 16) | bf16bits(tile[tc2][fr]);
    long off = (long)b * 131072 + (long)(f0 + fr) * 512 + t0 + tc2;
    *(uint*)(outT + off) = u;
  }
}

// ---------------------------------------------------------------------------
// Fused fwd DFT + freq op + transpose.
__global__ __launch_bounds__(256) void k_dftfreq(const ushort* __restrict__ CS2B,
                                                 const ushort* __restrict__ H1NTB,
                                                 const float* __restrict__ rd,
                                                 const float* __restrict__ idg,
                                                 const float* __restrict__ rb,
                                                 const float* __restrict__ ib,
                                                 ushort* __restrict__ XRITB) {
  int b = blockIdx.z;
  int lane = threadIdx.x & 63, wid = threadIdx.x >> 6;
  int m0 = blockIdx.y * 64 + wid * 16;   // freq rows 0..511
  int n0 = blockIdx.x * 64;              // feature cols
  const ushort* acrow = CS2B + (long)(m0 + (lane & 15)) * 512 + (lane >> 4) * 8;
  const ushort* asrow = acrow + 512L * 512;
  const ushort* brow = H1NTB + (long)b * 131072 + (long)(n0 + (lane & 15)) * 512 + (lane >> 4) * 8;
  f32x4 aC[4] = {{0.f, 0.f, 0.f, 0.f}, {0.f, 0.f, 0.f, 0.f},
                 {0.f, 0.f, 0.f, 0.f}, {0.f, 0.f, 0.f, 0.f}};
  f32x4 aS[4] = {{0.f, 0.f, 0.f, 0.f}, {0.f, 0.f, 0.f, 0.f},
                 {0.f, 0.f, 0.f, 0.f}, {0.f, 0.f, 0.f, 0.f}};
#pragma unroll 2
  for (int k0 = 0; k0 < 512; k0 += 32) {
    short8 avc = *(const short8*)(acrow + k0);
    short8 avs = *(const short8*)(asrow + k0);
#pragma unroll
    for (int c = 0; c < 4; ++c) {
      short8 bv = *(const short8*)(brow + (long)c * 16 * 512 + k0);
      aC[c] = __builtin_amdgcn_mfma_f32_16x16x32_bf16(avc, bv, aC[c], 0, 0, 0);
      aS[c] = __builtin_amdgcn_mfma_f32_16x16x32_bf16(avs, bv, aS[c], 0, 0, 0);
    }
  }
  int r0 = (lane >> 4) * 4, c0 = lane & 15;
#pragma unroll
  for (int c = 0; c < 4; ++c) {
    int f = n0 + c * 16 + c0;
    float rdv = rd[f], idv = idg[f], rbv = rb[f], ibv = ib[f];
    ushort pr[4], pi[4];
#pragma unroll
    for (int j = 0; j < 4; ++j) {
      float xr = aC[c][j], xi = aS[c][j];
      pr[j] = bf16bits(fmaxf(xr * rdv - xi * idv + rbv, 0.f));
      pi[j] = bf16bits(fmaxf(xi * rdv + xr * idv + ibv, 0.f));
    }
    long base = (long)b * 262144 + (long)f * 1024 + m0 + r0;
    uint2 ur = make_uint2(((uint)pr[1] << 16) | pr[0], ((uint)pr[3] << 16) | pr[2]);
    uint2 ui = make_uint2(((uint)pi[1] << 16) | pi[0], ((uint)pi[3] << 16) | pi[2]);
    *(uint2*)(XRITB + base) = ur;
    *(uint2*)(XRITB + base + 512) = ui;
  }
}

// ---------------------------------------------------------------------------
__global__ __launch_bounds__(256) void k_final(const float* __restrict__ xo,
                                               const ushort* __restrict__ f2b,
                                               const float* __restrict__ SQ,
                                               const float* __restrict__ g,
                                               const float* __restrict__ bb,
                                               float* __restrict__ out) {
  __shared__ float sc_s[128], sh_s[128];
  int tid = threadIdx.x;
  if (tid < 128) {
    float mu = SQ[tid] * (1.f / NT);
    float var = SQ[128 + tid] * (1.f / NT) - mu * mu;
    float sc = g[tid] * rsqrtf(var + EPSF);
    sc_s[tid] = sc;
    sh_s[tid] = bb[tid] - mu * sc;
  }
  __syncthreads();
  int i = blockIdx.x * 256 + tid;
  int c = i & 127;
  out[i] = xo[i] + fmaf(bfu(f2b[i]), sc_s[c], sh_s[c]);
}

// ---------------------------------------------------------------------------
extern "C" void kernel_launch(void* const* d_in, const int* in_sizes, int n_in,
                              void* d_out, int out_size, void* d_ws, size_t ws_size,
                              hipStream_t stream) {
  const float* x         = (const float*)d_in[0];
  const float* ln_w      = (const float*)d_in[1];
  const float* ln_b      = (const float*)d_in[2];
  const float* in_proj_w = (const float*)d_in[3];
  const float* conv_w    = (const float*)d_in[4];
  const float* conv_b    = (const float*)d_in[5];
  const float* x_proj_w  = (const float*)d_in[6];
  const float* dt_proj_w = (const float*)d_in[7];
  const float* dt_proj_b = (const float*)d_in[8];
  const float* A_log     = (const float*)d_in[9];
  const float* D_param   = (const float*)d_in[10];
  const float* out_proj_w= (const float*)d_in[11];
  const float* n1w       = (const float*)d_in[12];
  const float* n1b       = (const float*)d_in[13];
  const float* n2w       = (const float*)d_in[14];
  const float* n2b       = (const float*)d_in[15];
  const float* fc1_w     = (const float*)d_in[16];
  const float* bn1_g     = (const float*)d_in[17];
  const float* bn1_b     = (const float*)d_in[18];
  const float* r_mat     = (const float*)d_in[19];
  const float* i_mat     = (const float*)d_in[20];
  const float* rb        = (const float*)d_in[21];
  const float* ib        = (const float*)d_in[22];
  const float* fc2_w     = (const float*)d_in[23];
  const float* bn2_g     = (const float*)d_in[24];
  const float* bn2_b     = (const float*)d_in[25];
  float* ws  = (float*)d_ws;
  float* out = (float*)d_out;

  k_tables<<<4096, 256, 0, stream>>>(A_log, fc1_w, fc2_w, r_mat, i_mat,
                                     in_proj_w, x_proj_w, out_proj_w,
                                     x, ln_w, ln_b, ws);
  // xz = xn @ in_proj_w -> bf16 XZB
  k_gmfma<true><<<dim3(8, 32, 1), 256, 0, stream>>>(
      (const ushort*)(ws + O_XNB), (const ushort*)(ws + O_INPB), ws + O_XZB,
      2048, 512, 128, 0, 0, 0);
  k_conv4<<<2048, 256, 0, stream>>>((const ushort*)(ws + O_XZB), conv_w, conv_b,
                                    (ushort*)(ws + O_XHB));
  // dbl_v = xh_v @ x_proj^T -> fp32 DBL (N=136)
  k_gmfma<false><<<dim3(3, 32, 4), 256, 0, stream>>>(
      (const ushort*)(ws + O_XHB), (const ushort*)(ws + O_XPB), ws + O_DBL,
      2048, 136, 256, 524288L, 0, 278528L);
  k_prep<<<dim3(32, 6, 4), 256, 0, stream>>>(ws + O_DBL, (const ushort*)(ws + O_XHB),
                                             dt_proj_w, dt_proj_b, out + 262144,
                                             (uint*)(ws + O_DTDX), ws + O_BCT);
  k_scan<<<3840, 256, 0, stream>>>((const uint*)(ws + O_DTDX), ws + O_BCT,
                                   ws + O_A2, ws + O_YS);
  k_yfull<<<2048, 256, 0, stream>>>(ws + O_YS, (const ushort*)(ws + O_XHB),
                                    (const ushort*)(ws + O_XZB), D_param,
                                    (ushort*)(ws + O_YACCB));
  // x_o = yacc @ out_proj_w -> fp32 XO1
  k_gmfma<false><<<dim3(2, 32, 1), 256, 0, stream>>>(
      (const ushort*)(ws + O_YACCB), (const ushort*)(ws + O_OPB), ws + O_XO1,
      2048, 128, 256, 0, 0, 0);
  k_lndbl<<<512, 256, 0, stream>>>(x, ws + O_XO1, n1w, n1b, n2w, n2b,
                                   ws + O_XO, (ushort*)(ws + O_LN2B));
  // h1 = LN2b @ FC1b^T -> bf16 H1B + SQ1 stats
  k_gmfma_bn<<<dim3(4, 32), 256, 0, stream>>>(
      (const ushort*)(ws + O_LN2B), (const ushort*)(ws + O_FC1B),
      (ushort*)(ws + O_H1B), ws + O_SQ1, 256, 128);
  k_bnreluT<<<dim3(8, 4, 4), 256, 0, stream>>>((const ushort*)(ws + O_H1B),
                                               ws + O_SQ1, bn1_g, bn1_b,
                                               (ushort*)(ws + O_H1NTB));
  // fused fwd DFT + freq + transpose -> XRITB bf16
  k_dftfreq<<<dim3(4, 8, 4), 256, 0, stream>>>(
      (const ushort*)(ws + O_CS2B), (const ushort*)(ws + O_H1NTB),
      ws + O_RD, ws + O_IDG, rb, ib, (ushort*)(ws + O_XRITB));
  // inv DFT: H2b_b = CSIb @ XRITb_b^T -> bf16
  k_gmfma<true><<<dim3(4, 8, 4), 256, 0, stream>>>(
      (const ushort*)(ws + O_CSIB), (const ushort*)(ws + O_XRITB), ws + O_H2B,
      512, 256, 1024, 0, 262144L, 131072L);
  // f2 = H2b @ FC2b^T -> bf16 F2B + SQ2 stats
  k_gmfma_bn<<<dim3(2, 32), 256, 0, stream>>>(
      (const ushort*)(ws + O_H2B), (const ushort*)(ws + O_FC2B),
      (ushort*)(ws + O_F2B), ws + O_SQ2, 128, 256);
  k_final<<<1024, 256, 0, stream>>>(ws + O_XO, (const ushort*)(ws + O_F2B),
                                    ws + O_SQ2, bn2_g, bn2_b, out);
}

// Round 14
// 268.174 us; speedup vs baseline: 1.2969x; 1.0721x over previous
//
#include <hip/hip_runtime.h>
#include <hip/hip_bf16.h>
#include <math.h>

// ---------------------------------------------------------------------------
// SABlock_CrossMamba. R14 = R13 + (a) scan reduce via fused v_add_f32_dpp
// (1 instr/stage, was mov+add); (b) small GEMMs (out_proj/h1/f2/dftfreq/
// invDFT) as 1-wave 64-thread blocks -> 4x grid for latency hiding.
// ---------------------------------------------------------------------------

constexpr int NT = 2048;
constexpr int Di = 256;
constexpr float EPSF = 1e-5f;
constexpr float LOG2E = 1.4426950408889634f;
constexpr float ISQ512 = 0.04419417382415922f;  // 1/sqrt(512)

typedef __attribute__((ext_vector_type(8))) short short8;
typedef __attribute__((ext_vector_type(4))) float f32x4;

// ws layout (float offsets, 16B-aligned)
constexpr long O_CS2B  = 0;         // bf16 1024x512
constexpr long O_CSIB  = 262144;    // bf16 512x1024
constexpr long O_A2    = 524288;    // 16384 fl
constexpr long O_FC1B  = 540672;    // bf16 256x128
constexpr long O_FC2B  = 557056;    // bf16 128x256
constexpr long O_INPB  = 573440;    // bf16 512x128
constexpr long O_XPB   = 606208;    // bf16 192x256 (x_proj^T, pad n>=136)
constexpr long O_OPB   = 630784;    // bf16 128x256
constexpr long O_RD    = 647168;    // 256
constexpr long O_IDG   = 647424;    // 256
constexpr long O_XNB   = 647680;    // bf16 2048x128
constexpr long O_XZB   = 778752;    // bf16 2048x512
constexpr long O_XHB   = 1303040;   // bf16 4x2048x256
constexpr long O_DBL   = 2351616;   // fp32 4x2048x136 (1114112 fl)
constexpr long O_DTDX  = 3465728;   // uint 4x256x2048 (bf16 dt|dx pair)
constexpr long O_BCT   = 5562880;   // fp32 4x2048x128 (B|C packed)
constexpr long O_YS    = 6611456;   // fp32 4x2048x256
constexpr long O_XO    = 8708608;   // fp32 2048x128
constexpr long O_LN2B  = 8970752;   // bf16 2048x128
constexpr long O_H1B   = 9101824;   // bf16 2048x256
constexpr long O_H1NTB = 9363968;   // bf16 4x256x512
constexpr long O_XRITB = 9626112;   // bf16 4x256x1024 (524288 fl)
constexpr long O_H2B   = 10150400;  // bf16 2048x256
constexpr long O_F2B   = 10412544;  // bf16 2048x128
constexpr long O_SQ1   = 10543616;  // 512
constexpr long O_SQ2   = 10544128;  // 256
// Aliases (disjoint lifetimes):
constexpr long O_XO1   = O_XRITB;   // out_proj->lndbl; XRITB written later
constexpr long O_YACCB = O_DBL;     // yfull->out_proj; DBL dead after k_prep

__device__ __forceinline__ ushort bf16bits(float v) {
  __hip_bfloat16 h = __float2bfloat16(v);
  return *(ushort*)&h;
}
__device__ __forceinline__ float bfu(ushort u) {
  return __uint_as_float((uint)u << 16);
}

// ---------------------------------------------------------------------------
__global__ __launch_bounds__(256) void k_tables(
    const float* __restrict__ A_log, const float* __restrict__ fc1_w,
    const float* __restrict__ fc2_w, const float* __restrict__ r_mat,
    const float* __restrict__ i_mat, const float* __restrict__ in_proj_w,
    const float* __restrict__ x_proj_w, const float* __restrict__ out_proj_w,
    const float* __restrict__ x, const float* __restrict__ ln_w,
    const float* __restrict__ ln_b, float* __restrict__ ws) {
  __shared__ float ct[512];
  int tid = threadIdx.x;
  ct[tid]       = __cosf((float)tid * (6.283185307179586f / 512.0f)) * ISQ512;
  ct[tid + 256] = __cosf((float)(tid + 256) * (6.283185307179586f / 512.0f)) * ISQ512;
  __syncthreads();
  __hip_bfloat16* cs2b = (__hip_bfloat16*)(ws + O_CS2B);
  __hip_bfloat16* csib = (__hip_bfloat16*)(ws + O_CSIB);
  int i = blockIdx.x * 256 + tid;   // 1048576 threads
  if (i < 524288) {          // CS2[r][n]: r<512 cos(rn), else -sin((r-512)n)
    int r = i >> 9, n = i & 511;
    float v;
    if (r < 512) v = ct[(r * n) & 511];
    else         v = -ct[((r - 512) * n + 384) & 511];
    cs2b[i] = __float2bfloat16(v);
  } else {                   // CSI[n][kp]: kp<512 cos(n*kp), else -sin(n(kp-512))
    int j = i - 524288;
    int n = j >> 10, kp = j & 1023;
    float v;
    if (kp < 512) v = ct[(n * kp) & 511];
    else          v = -ct[(n * (kp - 512) + 384) & 511];
    csib[j] = __float2bfloat16(v);
  }
  if (i < 16384) ws[O_A2 + i] = -expf(A_log[i]) * LOG2E;
  if (i < 32768) {
    ((__hip_bfloat16*)(ws + O_FC1B))[i] = __float2bfloat16(fc1_w[i]);
    ((__hip_bfloat16*)(ws + O_FC2B))[i] = __float2bfloat16(fc2_w[i]);
  }
  if (i < 65536) {  // INPB[n][k] = in_proj_w[k][n]  (512x128)
    int n = i >> 7, k = i & 127;
    ((__hip_bfloat16*)(ws + O_INPB))[i] = __float2bfloat16(in_proj_w[k * 512 + n]);
  }
  if (i < 49152) {  // XPB[n][k] = x_proj_w[k][n], zero pad n>=136 (192x256)
    int n = i >> 8, k = i & 255;
    float v = (n < 136) ? x_proj_w[k * 136 + n] : 0.f;
    ((__hip_bfloat16*)(ws + O_XPB))[i] = __float2bfloat16(v);
  }
  if (i >= 65536 && i < 98304) {  // OPB[n][k] = out_proj_w[k][n] (128x256)
    int j = i - 65536;
    int n = j >> 8, k = j & 255;
    ((__hip_bfloat16*)(ws + O_OPB))[j] = __float2bfloat16(out_proj_w[k * 128 + n]);
  }
  if (i < 256) {
    ws[O_RD + i] = r_mat[i * 256 + i];
    ws[O_IDG + i] = i_mat[i * 256 + i];
  }
  if (i < 512) ws[O_SQ1 + i] = 0.f;
  if (i < 256) ws[O_SQ2 + i] = 0.f;
  if (blockIdx.x < 512) {  // ln1, one wave per token
    ushort* outb = (ushort*)(ws + O_XNB);
    int lane = tid & 63;
    int t = (blockIdx.x * 256 + tid) >> 6;
    float v0 = x[t * 128 + lane], v1 = x[t * 128 + 64 + lane];
    float s = v0 + v1, sq = v0 * v0 + v1 * v1;
#pragma unroll
    for (int off = 32; off; off >>= 1) { s += __shfl_xor(s, off); sq += __shfl_xor(sq, off); }
    float mu = s * (1.f / 128.f);
    float rstd = rsqrtf(sq * (1.f / 128.f) - mu * mu + EPSF);
    outb[t * 128 + lane]      = bf16bits((v0 - mu) * rstd * ln_w[lane] + ln_b[lane]);
    outb[t * 128 + 64 + lane] = bf16bits((v1 - mu) * rstd * ln_w[64 + lane] + ln_b[64 + lane]);
  }
}

// ---------------------------------------------------------------------------
__global__ void k_lndbl(const float* __restrict__ x, const float* __restrict__ xo1,
                        const float* __restrict__ w1, const float* __restrict__ b1,
                        const float* __restrict__ w2, const float* __restrict__ b2,
                        float* __restrict__ xo, ushort* __restrict__ ln2b) {
  int lane = threadIdx.x & 63;
  int t = (blockIdx.x * 256 + threadIdx.x) >> 6;
  float u0 = xo1[t * 128 + lane], u1 = xo1[t * 128 + 64 + lane];
  float s = u0 + u1, sq = u0 * u0 + u1 * u1;
#pragma unroll
  for (int off = 32; off; off >>= 1) { s += __shfl_xor(s, off); sq += __shfl_xor(sq, off); }
  float mu = s * (1.f / 128.f);
  float rstd = rsqrtf(sq * (1.f / 128.f) - mu * mu + EPSF);
  float a0 = x[t * 128 + lane]      + (u0 - mu) * rstd * w1[lane] + b1[lane];
  float a1 = x[t * 128 + 64 + lane] + (u1 - mu) * rstd * w1[64 + lane] + b1[64 + lane];
  xo[t * 128 + lane] = a0;
  xo[t * 128 + 64 + lane] = a1;
  s = a0 + a1; sq = a0 * a0 + a1 * a1;
#pragma unroll
  for (int off = 32; off; off >>= 1) { s += __shfl_xor(s, off); sq += __shfl_xor(sq, off); }
  mu = s * (1.f / 128.f);
  rstd = rsqrtf(sq * (1.f / 128.f) - mu * mu + EPSF);
  ln2b[t * 128 + lane]      = bf16bits((a0 - mu) * rstd * w2[lane] + b2[lane]);
  ln2b[t * 128 + 64 + lane] = bf16bits((a1 - mu) * rstd * w2[64 + lane] + b2[64 + lane]);
}

// ---------------------------------------------------------------------------
// bf16 MFMA GEMM: C = A @ Bt^T. NW waves/block, 16 rows each. n < N guarded.
template <int NW, bool OUTBF16>
__global__ __launch_bounds__(NW * 64) void k_gmfma(const ushort* __restrict__ A,
                                                   const ushort* __restrict__ Bt,
                                                   void* __restrict__ Cv,
                                                   int M, int N, int K,
                                                   long sA, long sBt, long sC) {
  A += (long)blockIdx.z * sA;
  Bt += (long)blockIdx.z * sBt;
  int lane = threadIdx.x & 63, wid = threadIdx.x >> 6;
  int m0 = blockIdx.y * (NW * 16) + wid * 16, n0 = blockIdx.x * 64;
  const ushort* arow = A + (long)(m0 + (lane & 15)) * K + (lane >> 4) * 8;
  const ushort* brow = Bt + (long)(n0 + (lane & 15)) * K + (lane >> 4) * 8;
  f32x4 acc0 = {0.f, 0.f, 0.f, 0.f}, acc1 = acc0, acc2 = acc0, acc3 = acc0;
#pragma unroll 4
  for (int k0 = 0; k0 < K; k0 += 32) {
    short8 av = *(const short8*)(arow + k0);
    short8 b0 = *(const short8*)(brow + k0);
    short8 b1 = *(const short8*)(brow + 16L * K + k0);
    short8 b2 = *(const short8*)(brow + 32L * K + k0);
    short8 b3 = *(const short8*)(brow + 48L * K + k0);
    acc0 = __builtin_amdgcn_mfma_f32_16x16x32_bf16(av, b0, acc0, 0, 0, 0);
    acc1 = __builtin_amdgcn_mfma_f32_16x16x32_bf16(av, b1, acc1, 0, 0, 0);
    acc2 = __builtin_amdgcn_mfma_f32_16x16x32_bf16(av, b2, acc2, 0, 0, 0);
    acc3 = __builtin_amdgcn_mfma_f32_16x16x32_bf16(av, b3, acc3, 0, 0, 0);
  }
  int r0 = (lane >> 4) * 4, c0 = lane & 15;
#pragma unroll
  for (int j = 0; j < 4; ++j) {
    long row = m0 + r0 + j;
    float v[4] = {acc0[j], acc1[j], acc2[j], acc3[j]};
    if (OUTBF16) {
      __hip_bfloat16* C = (__hip_bfloat16*)Cv + blockIdx.z * sC;
#pragma unroll
      for (int c = 0; c < 4; ++c) {
        int n = n0 + c * 16 + c0;
        if (n < N) C[row * N + n] = __float2bfloat16(v[c]);
      }
    } else {
      float* C = (float*)Cv + blockIdx.z * sC;
#pragma unroll
      for (int c = 0; c < 4; ++c) {
        int n = n0 + c * 16 + c0;
        if (n < N) C[row * N + n] = v[c];
      }
    }
  }
}

// bf16 MFMA GEMM + per-column BN partial stats (atomics). 1-wave blocks.
__global__ __launch_bounds__(64) void k_gmfma_bn(const ushort* __restrict__ A,
                                                 const ushort* __restrict__ Bt,
                                                 ushort* __restrict__ C,
                                                 float* __restrict__ SQ,
                                                 int N, int K) {
  int lane = threadIdx.x & 63;
  int m0 = blockIdx.y * 16, n0 = blockIdx.x * 64;
  const ushort* arow = A + (long)(m0 + (lane & 15)) * K + (lane >> 4) * 8;
  const ushort* brow = Bt + (long)(n0 + (lane & 15)) * K + (lane >> 4) * 8;
  f32x4 acc[4] = {{0.f, 0.f, 0.f, 0.f}, {0.f, 0.f, 0.f, 0.f},
                  {0.f, 0.f, 0.f, 0.f}, {0.f, 0.f, 0.f, 0.f}};
#pragma unroll 4
  for (int k0 = 0; k0 < K; k0 += 32) {
    short8 av = *(const short8*)(arow + k0);
#pragma unroll
    for (int c = 0; c < 4; ++c) {
      short8 bv = *(const short8*)(brow + (long)c * 16 * K + k0);
      acc[c] = __builtin_amdgcn_mfma_f32_16x16x32_bf16(av, bv, acc[c], 0, 0, 0);
    }
  }
  int r0 = (lane >> 4) * 4, c0 = lane & 15;
#pragma unroll
  for (int j = 0; j < 4; ++j) {
    long row = m0 + r0 + j;
#pragma unroll
    for (int c = 0; c < 4; ++c)
      C[row * N + n0 + c * 16 + c0] = bf16bits(acc[c][j]);
  }
#pragma unroll
  for (int c = 0; c < 4; ++c) {
    f32x4 v = acc[c];
    float s = v[0] + v[1] + v[2] + v[3];
    float q = v[0] * v[0] + v[1] * v[1] + v[2] * v[2] + v[3] * v[3];
    s += __shfl_xor(s, 16); s += __shfl_xor(s, 32);
    q += __shfl_xor(q, 16); q += __shfl_xor(q, 32);
    if ((lane >> 4) == 0) {
      int n = n0 + c * 16 + c0;
      atomicAdd(&SQ[n], s);
      atomicAdd(&SQ[N + n], q);
    }
  }
}

// ---------------------------------------------------------------------------
// Causal depthwise conv + SiLU, all 4 variants per thread (bf16 in/out).
__global__ void k_conv4(const ushort* __restrict__ xzb, const float* __restrict__ cw,
                        const float* __restrict__ cb, ushort* __restrict__ xhb) {
  int i = blockIdx.x * 256 + threadIdx.x;
  int t = i >> 8, d = i & 255;
  float w0 = cw[d * 4 + 0], w1 = cw[d * 4 + 1], w2 = cw[d * 4 + 2], w3 = cw[d * 4 + 3];
  float bias = cb[d];
  float x0  = bfu(xzb[(long)t * 512 + d]);
  float xm1 = t >= 1 ? bfu(xzb[(long)(t - 1) * 512 + d]) : 0.f;
  float xm2 = t >= 2 ? bfu(xzb[(long)(t - 2) * 512 + d]) : 0.f;
  float xm3 = t >= 3 ? bfu(xzb[(long)(t - 3) * 512 + d]) : 0.f;
  if ((t & 63) >= 3) {
    float s = fmaf(w0, xm3, fmaf(w1, xm2, fmaf(w2, xm1, fmaf(w3, x0, bias))));
    float sil = s / (1.f + expf(-s));
    ushort sb = bf16bits(sil);
#pragma unroll
    for (int v = 0; v < 4; ++v) xhb[v * 524288 + i] = sb;
  } else {
#pragma unroll
    for (int v = 0; v < 4; ++v) {
      int lv = t & ((512 >> v) - 1);
      float s = fmaf(w3, x0, bias);
      if (lv >= 1) s = fmaf(w2, xm1, s);
      if (lv >= 2) s = fmaf(w1, xm2, s);
      if (lv >= 3) s = fmaf(w0, xm3, s);
      float sil = s / (1.f + expf(-s));
      xhb[v * 524288 + i] = bf16bits(sil);
    }
  }
}

// ---------------------------------------------------------------------------
// prep: grid (32 t-tiles, 6 tasks, 4 v) = 768 blocks.
__global__ __launch_bounds__(256) void k_prep(const float* __restrict__ dbl,
                                              const ushort* __restrict__ xhb,
                                              const float* __restrict__ dtw,
                                              const float* __restrict__ dt_b,
                                              float* __restrict__ outC,
                                              uint* __restrict__ DTDX,
                                              float* __restrict__ BCT) {
  int t0 = blockIdx.x * 64, task = blockIdx.y, v = blockIdx.z;
  int tid = threadIdx.x;
  const float* dp = dbl + ((long)v * 2048 + t0) * 136;
  if (task < 4) {
    __shared__ float r8T[8][64];
    __shared__ float wt[8][64];
    __shared__ uint tile[64][65];
    int d0 = task * 64;
    if (tid < 128) {
      int t = tid >> 1, half = tid & 1;
      float4 q = *(const float4*)&dp[(long)t * 136 + half * 4];
      r8T[half * 4 + 0][t] = q.x; r8T[half * 4 + 1][t] = q.y;
      r8T[half * 4 + 2][t] = q.z; r8T[half * 4 + 3][t] = q.w;
    } else {
      int idx = tid - 128;
      int r = idx >> 4, dl4 = (idx & 15) * 4;
      float4 q = *(const float4*)&dtw[r * 256 + d0 + dl4];
      wt[r][dl4] = q.x; wt[r][dl4 + 1] = q.y; wt[r][dl4 + 2] = q.z; wt[r][dl4 + 3] = q.w;
    }
    __syncthreads();
#pragma unroll
    for (int it = 0; it < 16; ++it) {
      int idx = it * 256 + tid;
      int t = idx >> 6, dl = idx & 63;
      int d = d0 + dl;
      float s = dt_b[d];
#pragma unroll
      for (int r = 0; r < 8; ++r) s = fmaf(r8T[r][t], wt[r][dl], s);
      float dtv = fmaxf(s, 0.f) + log1pf(expf(-fabsf(s)));
      float xv = bfu(xhb[((long)v * 2048 + t0 + t) * 256 + d]);
      tile[t][dl] = ((uint)bf16bits(dtv * xv) << 16) | (uint)bf16bits(dtv);
    }
    __syncthreads();
#pragma unroll
    for (int it = 0; it < 16; ++it) {
      int idx = it * 256 + tid;
      int dl = idx >> 6, t = idx & 63;
      DTDX[((long)(v * 256 + d0 + dl)) * 2048 + t0 + t] = tile[t][dl];
    }
  } else if (task == 4) {
    float* bout = BCT + ((long)v * 2048 + t0) * 128;
#pragma unroll
    for (int it = 0; it < 32; ++it) {
      int idx = it * 256 + tid;
      int t = idx >> 7, j = idx & 127;
      bout[idx] = dp[(long)t * 136 + 8 + j];
    }
  } else {
#pragma unroll
    for (int it = 0; it < 16; ++it) {
      int idx = it * 256 + tid;
      int t = idx >> 6, s = idx & 63;
      outC[(long)v * 131072 + (long)(t0 + t) * 64 + s] = dp[(long)t * 136 + 72 + s];
    }
  }
}

// ---------------------------------------------------------------------------
// Fused single-instruction DPP add: x += dpp(x). bound_ctrl:0 => 0-fill.
#define DPPA(x, CTRL)                                                        \
  { float _t;                                                                \
    asm("v_add_f32_dpp %0, %1, %2 " CTRL                                     \
        " row_mask:0xf bank_mask:0xf bound_ctrl:0"                           \
        : "=v"(_t) : "v"(x), "v"(x));                                        \
    x = _t; }

// Selective scan: packed dt/dx, packed B|C rows, fused-DPP reduce, writelane.
__global__ __launch_bounds__(256) void k_scan(const uint* __restrict__ DTDX,
                                              const float* __restrict__ BCT,
                                              const float* __restrict__ A2,
                                              float* __restrict__ ys) {
  int lane = threadIdx.x & 63;
  int gwid = (blockIdx.x * 256 + threadIdx.x) >> 6;
  int v, base;
  if (gwid < 1024)      { v = 0; base = 0; }
  else if (gwid < 3072) { v = 1; base = 1024; }
  else if (gwid < 7168) { v = 2; base = 3072; }
  else                  { v = 3; base = 7168; }
  int local = gwid - base;
  int b = local >> 8, d = local & 255;
  int Lp = 512 >> v;
  int t0 = b * Lp;
  const uint* drow = DTDX + ((long)(v * 256 + d)) * 2048 + t0;
  const float* brow = BCT + ((long)(v * 2048 + t0)) * 128;
  float* ysp = ys + (long)v * NT * Di + (long)((b << 8) + d) * Lp;
  float a2 = A2[d * 64 + lane];
  float h = 0.f;

#define LOADG(BB, CC, G)                                                     \
  { const float* rg = rowp + (G) * 1024;                                     \
    _Pragma("unroll") for (int q = 0; q < 8; ++q) {                          \
      BB[q] = rg[q * 128 + lane];                                            \
      CC[q] = rg[q * 128 + 64 + lane];                                       \
    } }
#define PROCG(BB, CC, G)                                                     \
  _Pragma("unroll") for (int q = 0; q < 8; ++q) {                            \
    const int l2 = (G) * 8 + q;                                              \
    uint u = (uint)__builtin_amdgcn_readlane((int)rdx, l2);                  \
    float sdt = __uint_as_float(u << 16);                                    \
    float sdx = __uint_as_float(u & 0xffff0000u);                            \
    float a = __builtin_amdgcn_exp2f(sdt * a2);                              \
    h = fmaf(a, h, sdx * BB[q]);                                             \
    float p = h * CC[q];                                                     \
    DPPA(p, "row_shr:1") DPPA(p, "row_shr:2")                                \
    DPPA(p, "row_shr:4") DPPA(p, "row_shr:8")                                \
    DPPA(p, "row_bcast:15") DPPA(p, "row_bcast:31")                          \
    int tot = __builtin_amdgcn_readlane(__float_as_int(p), 63);              \
    asm("v_writelane_b32 %0, %1, %2" : "+v"(ybuf_i) : "s"(tot), "i"(l2));    \
  }

  for (int c = 0; c < Lp; c += 64) {
    uint rdx = drow[c + lane];
    const float* rowp = brow + (long)c * 128;
    int ybuf_i = 0;
    float b0[8], c0[8], b1[8], c1[8];
    LOADG(b0, c0, 0)
    LOADG(b1, c1, 1)
    PROCG(b0, c0, 0) LOADG(b0, c0, 2)
    PROCG(b1, c1, 1) LOADG(b1, c1, 3)
    PROCG(b0, c0, 2) LOADG(b0, c0, 4)
    PROCG(b1, c1, 3) LOADG(b1, c1, 5)
    PROCG(b0, c0, 4) LOADG(b0, c0, 6)
    PROCG(b1, c1, 5) LOADG(b1, c1, 7)
    PROCG(b0, c0, 6)
    PROCG(b1, c1, 7)
    ysp[c + lane] = __int_as_float(ybuf_i);
  }
#undef LOADG
#undef PROCG
}

// ---------------------------------------------------------------------------
__global__ void k_yfull(const float* __restrict__ ys, const ushort* __restrict__ xhb,
                        const ushort* __restrict__ xzb, const float* __restrict__ Dp,
                        ushort* __restrict__ yaccb) {
  int i = blockIdx.x * 256 + threadIdx.x;
  int t = i >> 8, d = i & 255;
  float z = bfu(xzb[(long)t * 512 + 256 + d]);
  float sil = z / (1.f + expf(-z));
  float Dd = Dp[d];
  float s = 0.f;
#pragma unroll
  for (int v = 0; v < 4; ++v) {
    int Lp = 512 >> v;
    int b = t >> (9 - v);
    int l = t & (Lp - 1);
    float ysv = ys[(long)v * NT * Di + (long)((b << 8) + d) * Lp + l];
    float xhv = bfu(xhb[(long)v * 524288 + i]);
    s += ysv + Dd * xhv;
  }
  yaccb[i] = bf16bits(s * sil);
}

// ---------------------------------------------------------------------------
// bnrelu + transpose-convert from bf16 H1B; scale/shift inline from SQ.
__global__ __launch_bounds__(256) void k_bnreluT(const ushort* __restrict__ h1b,
                                                 const float* __restrict__ SQ,
                                                 const float* __restrict__ g,
                                                 const float* __restrict__ bb,
                                                 ushort* __restrict__ outT) {
  __shared__ float tile[64][65];
  __shared__ float sc_s[64], sh_s[64];
  int t0 = blockIdx.x * 64, f0 = blockIdx.y * 64, b = blockIdx.z;
  int tid = threadIdx.x;
  if (tid < 64) {
    int f = f0 + tid;
    float mu = SQ[f] * (1.f / NT);
    float var = SQ[256 + f] * (1.f / NT) - mu * mu;
    float sc = g[f] * rsqrtf(var + EPSF);
    sc_s[tid] = sc;
    sh_s[tid] = bb[f] - mu * sc;
  }
  __syncthreads();
  const uint* h1u = (const uint*)h1b;
#pragma unroll
  for (int i = 0; i < 8; ++i) {
    int idx = i * 256 + tid;           // 2048 uints: r(64) x cu(32)
    int r = idx >> 5, cu = idx & 31;
    uint u = h1u[((long)(b * 512 + t0 + r)) * 128 + (f0 >> 1) + cu];
    int c = cu * 2;
    tile[r][c]     = fmaxf(fmaf(bfu((ushort)(u & 0xffff)), sc_s[c], sh_s[c]), 0.f);
    tile[r][c + 1] = fmaxf(fmaf(bfu((ushort)(u >> 16)), sc_s[c + 1], sh_s[c + 1]), 0.f);
  }
  __syncthreads();
  int tc2 = (tid & 31) * 2, fr0 = tid >> 5;
#pragma unroll
  for (int i = 0; i < 8; ++i) {
    int fr = fr0 + i * 8;
    uint u = ((uint)bf16bits(tile[tc2 + 1][fr]) << 16) | bf16bits(tile[tc2][fr]);
    long off = (long)b * 131072 + (long)(f0 + fr) * 512 + t0 + tc2;
    *(uint*)(outT + off) = u;
  }
}

// ---------------------------------------------------------------------------
// Fused fwd DFT + freq op + transpose. 1-wave blocks: m0 = blockIdx.y*16.
__global__ __launch_bounds__(64) void k_dftfreq(const ushort* __restrict__ CS2B,
                                                const ushort* __restrict__ H1NTB,
                                                const float* __restrict__ rd,
                                                const float* __restrict__ idg,
                                                const float* __restrict__ rb,
                                                const float* __restrict__ ib,
                                                ushort* __restrict__ XRITB) {
  int b = blockIdx.z;
  int lane = threadIdx.x & 63;
  int m0 = blockIdx.y * 16;              // freq rows 0..511
  int n0 = blockIdx.x * 64;              // feature cols
  const ushort* acrow = CS2B + (long)(m0 + (lane & 15)) * 512 + (lane >> 4) * 8;
  const ushort* asrow = acrow + 512L * 512;
  const ushort* brow = H1NTB + (long)b * 131072 + (long)(n0 + (lane & 15)) * 512 + (lane >> 4) * 8;
  f32x4 aC[4] = {{0.f, 0.f, 0.f, 0.f}, {0.f, 0.f, 0.f, 0.f},
                 {0.f, 0.f, 0.f, 0.f}, {0.f, 0.f, 0.f, 0.f}};
  f32x4 aS[4] = {{0.f, 0.f, 0.f, 0.f}, {0.f, 0.f, 0.f, 0.f},
                 {0.f, 0.f, 0.f, 0.f}, {0.f, 0.f, 0.f, 0.f}};
#pragma unroll 2
  for (int k0 = 0; k0 < 512; k0 += 32) {
    short8 avc = *(const short8*)(acrow + k0);
    short8 avs = *(const short8*)(asrow + k0);
#pragma unroll
    for (int c = 0; c < 4; ++c) {
      short8 bv = *(const short8*)(brow + (long)c * 16 * 512 + k0);
      aC[c] = __builtin_amdgcn_mfma_f32_16x16x32_bf16(avc, bv, aC[c], 0, 0, 0);
      aS[c] = __builtin_amdgcn_mfma_f32_16x16x32_bf16(avs, bv, aS[c], 0, 0, 0);
    }
  }
  int r0 = (lane >> 4) * 4, c0 = lane & 15;
#pragma unroll
  for (int c = 0; c < 4; ++c) {
    int f = n0 + c * 16 + c0;
    float rdv = rd[f], idv = idg[f], rbv = rb[f], ibv = ib[f];
    ushort pr[4], pi[4];
#pragma unroll
    for (int j = 0; j < 4; ++j) {
      float xr = aC[c][j], xi = aS[c][j];
      pr[j] = bf16bits(fmaxf(xr * rdv - xi * idv + rbv, 0.f));
      pi[j] = bf16bits(fmaxf(xi * rdv + xr * idv + ibv, 0.f));
    }
    long base = (long)b * 262144 + (long)f * 1024 + m0 + r0;
    uint2 ur = make_uint2(((uint)pr[1] << 16) | pr[0], ((uint)pr[3] << 16) | pr[2]);
    uint2 ui = make_uint2(((uint)pi[1] << 16) | pi[0], ((uint)pi[3] << 16) | pi[2]);
    *(uint2*)(XRITB + base) = ur;
    *(uint2*)(XRITB + base + 512) = ui;
  }
}

// ---------------------------------------------------------------------------
__global__ __launch_bounds__(256) void k_final(const float* __restrict__ xo,
                                               const ushort* __restrict__ f2b,
                                               const float* __restrict__ SQ,
                                               const float* __restrict__ g,
                                               const float* __restrict__ bb,
                                               float* __restrict__ out) {
  __shared__ float sc_s[128], sh_s[128];
  int tid = threadIdx.x;
  if (tid < 128) {
    float mu = SQ[tid] * (1.f / NT);
    float var = SQ[128 + tid] * (1.f / NT) - mu * mu;
    float sc = g[tid] * rsqrtf(var + EPSF);
    sc_s[tid] = sc;
    sh_s[tid] = bb[tid] - mu * sc;
  }
  __syncthreads();
  int i = blockIdx.x * 256 + tid;
  int c = i & 127;
  out[i] = xo[i] + fmaf(bfu(f2b[i]), sc_s[c], sh_s[c]);
}

// ---------------------------------------------------------------------------
extern "C" void kernel_launch(void* const* d_in, const int* in_sizes, int n_in,
                              void* d_out, int out_size, void* d_ws, size_t ws_size,
                              hipStream_t stream) {
  const float* x         = (const float*)d_in[0];
  const float* ln_w      = (const float*)d_in[1];
  const float* ln_b      = (const float*)d_in[2];
  const float* in_proj_w = (const float*)d_in[3];
  const float* conv_w    = (const float*)d_in[4];
  const float* conv_b    = (const float*)d_in[5];
  const float* x_proj_w  = (const float*)d_in[6];
  const float* dt_proj_w = (const float*)d_in[7];
  const float* dt_proj_b = (const float*)d_in[8];
  const float* A_log     = (const float*)d_in[9];
  const float* D_param   = (const float*)d_in[10];
  const float* out_proj_w= (const float*)d_in[11];
  const float* n1w       = (const float*)d_in[12];
  const float* n1b       = (const float*)d_in[13];
  const float* n2w       = (const float*)d_in[14];
  const float* n2b       = (const float*)d_in[15];
  const float* fc1_w     = (const float*)d_in[16];
  const float* bn1_g     = (const float*)d_in[17];
  const float* bn1_b     = (const float*)d_in[18];
  const float* r_mat     = (const float*)d_in[19];
  const float* i_mat     = (const float*)d_in[20];
  const float* rb        = (const float*)d_in[21];
  const float* ib        = (const float*)d_in[22];
  const float* fc2_w     = (const float*)d_in[23];
  const float* bn2_g     = (const float*)d_in[24];
  const float* bn2_b     = (const float*)d_in[25];
  float* ws  = (float*)d_ws;
  float* out = (float*)d_out;

  k_tables<<<4096, 256, 0, stream>>>(A_log, fc1_w, fc2_w, r_mat, i_mat,
                                     in_proj_w, x_proj_w, out_proj_w,
                                     x, ln_w, ln_b, ws);
  // xz = xn @ in_proj_w -> bf16 XZB (4-wave blocks, 256 blocks)
  k_gmfma<4, true><<<dim3(8, 32, 1), 256, 0, stream>>>(
      (const ushort*)(ws + O_XNB), (const ushort*)(ws + O_INPB), ws + O_XZB,
      2048, 512, 128, 0, 0, 0);
  k_conv4<<<2048, 256, 0, stream>>>((const ushort*)(ws + O_XZB), conv_w, conv_b,
                                    (ushort*)(ws + O_XHB));
  // dbl_v = xh_v @ x_proj^T -> fp32 DBL (N=136, 384 blocks)
  k_gmfma<4, false><<<dim3(3, 32, 4), 256, 0, stream>>>(
      (const ushort*)(ws + O_XHB), (const ushort*)(ws + O_XPB), ws + O_DBL,
      2048, 136, 256, 524288L, 0, 278528L);
  k_prep<<<dim3(32, 6, 4), 256, 0, stream>>>(ws + O_DBL, (const ushort*)(ws + O_XHB),
                                             dt_proj_w, dt_proj_b, out + 262144,
                                             (uint*)(ws + O_DTDX), ws + O_BCT);
  k_scan<<<3840, 256, 0, stream>>>((const uint*)(ws + O_DTDX), ws + O_BCT,
                                   ws + O_A2, ws + O_YS);
  k_yfull<<<2048, 256, 0, stream>>>(ws + O_YS, (const ushort*)(ws + O_XHB),
                                    (const ushort*)(ws + O_XZB), D_param,
                                    (ushort*)(ws + O_YACCB));
  // x_o = yacc @ out_proj_w -> fp32 XO1 (1-wave blocks, 256 blocks)
  k_gmfma<1, false><<<dim3(2, 128, 1), 64, 0, stream>>>(
      (const ushort*)(ws + O_YACCB), (const ushort*)(ws + O_OPB), ws + O_XO1,
      2048, 128, 256, 0, 0, 0);
  k_lndbl<<<512, 256, 0, stream>>>(x, ws + O_XO1, n1w, n1b, n2w, n2b,
                                   ws + O_XO, (ushort*)(ws + O_LN2B));
  // h1 = LN2b @ FC1b^T -> bf16 H1B + SQ1 stats (512 blocks)
  k_gmfma_bn<<<dim3(4, 128), 64, 0, stream>>>(
      (const ushort*)(ws + O_LN2B), (const ushort*)(ws + O_FC1B),
      (ushort*)(ws + O_H1B), ws + O_SQ1, 256, 128);
  k_bnreluT<<<dim3(8, 4, 4), 256, 0, stream>>>((const ushort*)(ws + O_H1B),
                                               ws + O_SQ1, bn1_g, bn1_b,
                                               (ushort*)(ws + O_H1NTB));
  // fused fwd DFT + freq + transpose -> XRITB bf16 (512 blocks)
  k_dftfreq<<<dim3(4, 32, 4), 64, 0, stream>>>(
      (const ushort*)(ws + O_CS2B), (const ushort*)(ws + O_H1NTB),
      ws + O_RD, ws + O_IDG, rb, ib, (ushort*)(ws + O_XRITB));
  // inv DFT: H2b_b = CSIb @ XRITb_b^T -> bf16 (512 blocks)
  k_gmfma<1, true><<<dim3(4, 32, 4), 64, 0, stream>>>(
      (const ushort*)(ws + O_CSIB), (const ushort*)(ws + O_XRITB), ws + O_H2B,
      512, 256, 1024, 0, 262144L, 131072L);
  // f2 = H2b @ FC2b^T -> bf16 F2B + SQ2 stats (256 blocks)
  k_gmfma_bn<<<dim3(2, 128), 64, 0, stream>>>(
      (const ushort*)(ws + O_H2B), (const ushort*)(ws + O_FC2B),
      (ushort*)(ws + O_F2B), ws + O_SQ2, 128, 256);
  k_final<<<1024, 256, 0, stream>>>(ws + O_XO, (const ushort*)(ws + O_F2B),
                                    ws + O_SQ2, bn2_g, bn2_b, out);
}